// Round 12
// baseline (701.500 us; speedup 1.0000x reference)
//
#include <hip/hip_runtime.h>
#include <math.h>

#define DIM   1024
#define NTOK  4096
#define TSEQ  1024
#define NHEAD 16
#define MPROT 256
#define EPSR  1.1920929e-07f
#define SA    64.0f
#define SW    256.0f
#define SPC   64.0f
#define MAXI  160

typedef __attribute__((ext_vector_type(8))) short          short8;
typedef __attribute__((ext_vector_type(8))) _Float16       half8;
typedef __attribute__((ext_vector_type(4))) _Float16       half4;
typedef __attribute__((ext_vector_type(4))) float          f32x4;
typedef __attribute__((ext_vector_type(4))) unsigned short us4;

static __device__ __forceinline__ float bf2f(unsigned short s) {
  union { unsigned int u; float f; } c; c.u = ((unsigned int)s) << 16; return c.f;
}
static __device__ __forceinline__ unsigned short f2bf(float f) {
  union { float f; unsigned int u; } c; c.f = f;
  return (unsigned short)((c.u + 0x7fffu + ((c.u >> 16) & 1u)) >> 16);
}
static __device__ __forceinline__ void gload16(void* lds, const void* g) {
  __builtin_amdgcn_global_load_lds(
      (__attribute__((address_space(1))) void*)const_cast<void*>(g),
      (__attribute__((address_space(3))) void*)lds, 16, 0, 0);
}

// XCD swizzle for dense split-GEMMs: stripe m-blocks across XCDs.
static __device__ __forceinline__ void tile_swz(int& m0, int& n0) {
  const int gx = gridDim.x;
  const int L = blockIdx.y * gx + blockIdx.x;
  const int xcd = L & 7;
  const int j = L >> 3;
  const int mbq = j / gx;
  const int nb = j - mbq * gx;
  m0 = ((mbq << 3) | xcd) << 7;
  n0 = nb << 7;
}

// ---------------- conversions ----------------
__global__ __launch_bounds__(256) void cvt_attn4_k(const float* __restrict__ wq,
                                                   const float* __restrict__ wk,
                                                   const float* __restrict__ wv,
                                                   const float* __restrict__ wo,
                                                   _Float16* __restrict__ dh,
                                                   _Float16* __restrict__ dl) {
  const int wi = blockIdx.y;
  const float* s = (wi == 0) ? wq : (wi == 1) ? wk : (wi == 2) ? wv : wo;
  const int i = blockIdx.x * 256 + threadIdx.x;
  const size_t off4 = ((size_t)wi << 20) >> 2;
  const float4 v = ((const float4*)s)[i];
  float a0 = v.x * SW, a1 = v.y * SW, a2 = v.z * SW, a3 = v.w * SW;
  half4 hv, lv;
  _Float16 h0 = (_Float16)a0; hv[0] = h0; lv[0] = (_Float16)(a0 - (float)h0);
  _Float16 h1 = (_Float16)a1; hv[1] = h1; lv[1] = (_Float16)(a1 - (float)h1);
  _Float16 h2 = (_Float16)a2; hv[2] = h2; lv[2] = (_Float16)(a2 - (float)h2);
  _Float16 h3 = (_Float16)a3; hv[3] = h3; lv[3] = (_Float16)(a3 - (float)h3);
  ((half4*)dh)[off4 + i] = hv; ((half4*)dl)[off4 + i] = lv;
}

__global__ __launch_bounds__(256) void cvt_moe_all_k(
    const float* s0, const float* s1, const float* s2, const float* s3,
    const float* s4, const float* s5, const float* s6, const float* s7,
    const float* s8, const float* s9, const float* s10, const float* s11,
    unsigned short* __restrict__ dst) {
  const int n4tab[12] = {524288, 524288, 524288, 524288, 524288, 524288,
                         1048576, 1048576, 524288, 262144, 524288, 524288};
  const size_t offtab[12] = {0, 2097152, 4194304, 6291456, 8388608, 10485760,
                             12582912, 16777216, 20971520, 23068672, 24117248, 26214400};
  const int wi = blockIdx.y;
  const int i = blockIdx.x * 256 + threadIdx.x;
  if (i >= n4tab[wi]) return;
  const float* s;
  switch (wi) {
    case 0: s = s0; break; case 1: s = s1; break; case 2: s = s2; break;
    case 3: s = s3; break; case 4: s = s4; break; case 5: s = s5; break;
    case 6: s = s6; break; case 7: s = s7; break; case 8: s = s8; break;
    case 9: s = s9; break; case 10: s = s10; break; default: s = s11; break;
  }
  const float4 v = ((const float4*)s)[i];
  us4 o; o[0] = f2bf(v.x); o[1] = f2bf(v.y); o[2] = f2bf(v.z); o[3] = f2bf(v.w);
  ((us4*)(dst + offtab[wi]))[i] = o;
}

// ---------------- RMS norms ----------------
__global__ __launch_bounds__(256) void rms_split_k(const float* __restrict__ in,
                                                   const float* __restrict__ wgt,
                                                   _Float16* __restrict__ oh,
                                                   _Float16* __restrict__ ol) {
  const int row = blockIdx.x, tid = threadIdx.x;
  const float4 v = ((const float4*)(in + (size_t)row * DIM))[tid];
  float ss = v.x * v.x + v.y * v.y + v.z * v.z + v.w * v.w;
#pragma unroll
  for (int o = 32; o; o >>= 1) ss += __shfl_xor(ss, o);
  __shared__ float red[4];
  if ((tid & 63) == 0) red[tid >> 6] = ss;
  __syncthreads();
  const float sc = rsqrtf((red[0] + red[1] + red[2] + red[3]) * (1.0f / DIM) + EPSR) * SA;
  const float4 wv = ((const float4*)wgt)[tid];
  float a[4] = {v.x * sc * wv.x, v.y * sc * wv.y, v.z * sc * wv.z, v.w * sc * wv.w};
  half4 hv, lv;
#pragma unroll
  for (int j = 0; j < 4; ++j) {
    _Float16 hh = (_Float16)a[j]; hv[j] = hh; lv[j] = (_Float16)(a[j] - (float)hh);
  }
  ((half4*)(oh + (size_t)row * DIM))[tid] = hv;
  ((half4*)(ol + (size_t)row * DIM))[tid] = lv;
}

// fused RMSNorm(bf16 out) + gate logits/softmax/top-2
__global__ __launch_bounds__(256) void rmsgate_k(const float* __restrict__ x2,
                                                 const float* __restrict__ n2w,
                                                 const float* __restrict__ gw,
                                                 unsigned short* __restrict__ xfb,
                                                 float* __restrict__ wts) {
  const int row = blockIdx.x, tid = threadIdx.x;
  const float4 v = ((const float4*)(x2 + (size_t)row * DIM))[tid];
  float ss = v.x * v.x + v.y * v.y + v.z * v.z + v.w * v.w;
#pragma unroll
  for (int o = 32; o; o >>= 1) ss += __shfl_xor(ss, o);
  __shared__ float red[4];
  __shared__ float redE[4][4];
  const int w = tid >> 6, lane = tid & 63;
  if (lane == 0) red[w] = ss;
  __syncthreads();
  const float sc = rsqrtf((red[0] + red[1] + red[2] + red[3]) * (1.0f / DIM) + EPSR);
  const float4 nw = ((const float4*)n2w)[tid];
  const float xn0 = v.x * sc * nw.x, xn1 = v.y * sc * nw.y;
  const float xn2 = v.z * sc * nw.z, xn3 = v.w * sc * nw.w;
  us4 ob; ob[0] = f2bf(xn0); ob[1] = f2bf(xn1); ob[2] = f2bf(xn2); ob[3] = f2bf(xn3);
  ((us4*)(xfb + (size_t)row * DIM))[tid] = ob;
#pragma unroll
  for (int e = 0; e < 4; ++e) {
    const float4 g = ((const float4*)(gw + (size_t)e * DIM))[tid];
    float d = xn0 * g.x + xn1 * g.y + xn2 * g.z + xn3 * g.w;
#pragma unroll
    for (int o = 32; o; o >>= 1) d += __shfl_xor(d, o);
    if (lane == 0) redE[w][e] = d;
  }
  __syncthreads();
  if (tid == 0) {
    float lg[4];
#pragma unroll
    for (int e = 0; e < 4; ++e) lg[e] = redE[0][e] + redE[1][e] + redE[2][e] + redE[3][e];
    const float mx = fmaxf(fmaxf(lg[0], lg[1]), fmaxf(lg[2], lg[3]));
    float pe[4]; float sum = 0.0f;
#pragma unroll
    for (int e = 0; e < 4; ++e) { pe[e] = __expf(lg[e] - mx); sum += pe[e]; }
#pragma unroll
    for (int e = 0; e < 4; ++e) pe[e] /= sum;
    int i1 = 0;
    for (int e = 1; e < 4; ++e) if (pe[e] > pe[i1]) i1 = e;
    int i2 = -1;
    for (int e = 0; e < 4; ++e) { if (e == i1) continue; if (i2 < 0 || pe[e] > pe[i2]) i2 = e; }
    const float s2 = pe[i1] + pe[i2] + 1e-8f;
    float o[4] = {0.f, 0.f, 0.f, 0.f};
    o[i1] = pe[i1] / s2; o[i2] = pe[i2] / s2;
    float4 r; r.x = o[0]; r.y = o[1]; r.z = o[2]; r.w = o[3];
    *(float4*)(wts + (size_t)row * 4) = r;
  }
}

// ---------------- routing + dense per-XCD work lists ----------------
struct MoeCfg { int nbn[4][4]; int ks[4][4]; };

__global__ __launch_bounds__(256) void route2_k(const float* __restrict__ wts,
                                                int* __restrict__ idxP,
                                                int* __restrict__ meta,
                                                int* __restrict__ work,
                                                MoeCfg cfg) {
  const int tid = threadIdx.x, w = tid >> 6, lane = tid & 63;
  __shared__ int wsum[4];
  __shared__ int baseS;
  int off = 0;
  for (int e = 0; e < 4; ++e) {
    if (tid == 0) baseS = 0;
    __syncthreads();
    for (int c = 0; c < 16; ++c) {
      const int tok = (c << 8) + tid;
      const bool pred = wts[(size_t)tok * 4 + e] > 0.0f;
      const unsigned long long m = __ballot(pred);
      const int lanepre = __popcll(m & ((1ull << lane) - 1ull));
      if (lane == 0) wsum[w] = __popcll(m);
      __syncthreads();
      int wpre = 0;
#pragma unroll
      for (int i = 0; i < 4; ++i) wpre += (i < w) ? wsum[i] : 0;
      const int tot = wsum[0] + wsum[1] + wsum[2] + wsum[3];
      if (pred) idxP[off + baseS + wpre + lanepre] = tok;
      __syncthreads();
      if (tid == 0) baseS += tot;
      __syncthreads();
    }
    const int cnt = baseS;
    const int padded = (cnt + 127) & ~127;
    for (int j = cnt + tid; j < padded; j += 256) idxP[off + j] = -1;
    if (tid == 0) meta[80 + e] = off;
    const int mb0 = off >> 7, nmb = padded >> 7;
    for (int j = tid; j < nmb; j += 256) meta[mb0 + j] = e;
    off += padded;
    __syncthreads();
  }
  for (int j = (off >> 7) + tid; j < 72; j += 256) meta[j] = -1;
  for (int j = tid; j < 4 * 8 * MAXI; j += 256) work[j] = -1;
  __syncthreads();
  if (tid < 32) {
    const int p = tid >> 3, x = tid & 7;
    int* wb = work + p * (8 * MAXI);
    int n = 0;
    const int totmb = off >> 7;
    for (int mb = x; mb < totmb; mb += 8) {
      const int e = meta[mb];
      const int nbn = cfg.nbn[p][e];
      const int ks = cfg.ks[p][e];
      for (int nb = 0; nb < nbn; ++nb)
        for (int k = 0; k < ks; ++k) {
          wb[n * 8 + x] = mb | (nb << 8) | (k << 16);
          ++n;
        }
    }
  }
}

// ---------------- packed grouped sparse bf16 GEMM ----------------
// dbuf LDS + counted vmcnt + raw barriers: next-tile loads stay in flight
// across the MFMA phase (T3/T4 pattern; never drain vmcnt to 0 mid-loop).
struct SubOpP {
  const unsigned short* A;
  const unsigned short* Bw;
  unsigned short* outb;
  const unsigned short* other;
  int K, nbn, act, ep, gath, ks;  // ep: 0 store, 1 silu*other, 2 scatter atomicAdd->outp (masked)
};
struct PhaseP { SubOpP op[4]; };  // indexed by expert

__global__ __launch_bounds__(256, 2) void gemm_moe_k(PhaseP ph,
                                                     const int* __restrict__ meta,
                                                     const int* __restrict__ idxP,
                                                     const float* __restrict__ wts,
                                                     float* __restrict__ outp,
                                                     const int* __restrict__ wk) {
  __shared__ unsigned short As[2][128][64];
  __shared__ unsigned short Bs[2][128][64];
  const int item = wk[blockIdx.y * 8 + blockIdx.x];
  if (item < 0) return;
  const int mb = item & 255;
  const int nb = (item >> 8) & 255;
  const int kpart = (item >> 16) & 3;
  const int e = meta[mb];
  SubOpP op;
  switch (e) {
    case 0: op = ph.op[0]; break;
    case 1: op = ph.op[1]; break;
    case 2: op = ph.op[2]; break;
    default: op = ph.op[3]; break;
  }
  const int m0p = mb << 7;
  const int lr0 = m0p - meta[80 + e];
  const int n0 = nb << 7;
  const int F = op.nbn << 7;
  const int K = op.K;
  const int tid = threadIdx.x;
  const int w = tid >> 6, lane = tid & 63;
  const int wr = ((w >> 1) << 6), wc = ((w & 1) << 6);
  const int rr = lane & 15, kgl = lane >> 4;
  const int srow = tid >> 3, sslot = tid & 7;

  int grow[4];
#pragma unroll
  for (int i = 0; i < 4; ++i) {
    const int r = (i << 5) + srow;
    if (op.gath) {
      const int t = idxP[m0p + r];
      grow[i] = (t < 0) ? 0 : t;
    } else {
      grow[i] = lr0 + r;
    }
  }

  f32x4 acc[4][4];
#pragma unroll
  for (int a_ = 0; a_ < 4; ++a_)
#pragma unroll
    for (int b_ = 0; b_ < 4; ++b_) acc[a_][b_] = (f32x4){0.f, 0.f, 0.f, 0.f};

  int kt0 = 0, ktN = K >> 6;
  if (op.ks > 1) { const int seg = ktN / op.ks; kt0 = kpart * seg; ktN = kt0 + seg; }

  // 8 gload_lds per wave per stage (4 A + 4 B)
  auto stage = [&](int buf, int kt) {
    const int k0 = kt << 6;
#pragma unroll
    for (int i = 0; i < 4; ++i) {
      const int r = (i << 5) + srow;
      const int ls = sslot ^ (r & 7);
      gload16(&As[buf][(i << 5) + (w << 3)][0], op.A + (size_t)grow[i] * K + k0 + (ls << 3));
      gload16(&Bs[buf][(i << 5) + (w << 3)][0], op.Bw + (size_t)(n0 + r) * K + k0 + (ls << 3));
    }
  };
  stage(0, kt0);
  for (int kt = kt0; kt < ktN; ++kt) {
    const int cur = (kt - kt0) & 1;
    if (kt + 1 < ktN) {
      stage(cur ^ 1, kt + 1);
      asm volatile("s_waitcnt vmcnt(8)" ::: "memory");  // wait cur's 8 only; next 8 stay in flight
    } else {
      asm volatile("s_waitcnt vmcnt(0)" ::: "memory");
    }
    __builtin_amdgcn_s_barrier();
    __builtin_amdgcn_sched_barrier(0);
    short8 af[4][2], bfr[4][2];
#pragma unroll
    for (int f = 0; f < 4; ++f) {
#pragma unroll
      for (int ks = 0; ks < 2; ++ks) {
        const int row = wr + (f << 4) + rr;
        const int kg = (ks << 2) + kgl;
        af[f][ks] = *(const short8*)&As[cur][row][(kg ^ (row & 7)) << 3];
        const int col = wc + (f << 4) + rr;
        bfr[f][ks] = *(const short8*)&Bs[cur][col][(kg ^ (col & 7)) << 3];
      }
    }
#pragma unroll
    for (int fi = 0; fi < 4; ++fi)
#pragma unroll
      for (int fj = 0; fj < 4; ++fj)
#pragma unroll
        for (int ks = 0; ks < 2; ++ks)
          acc[fi][fj] = __builtin_amdgcn_mfma_f32_16x16x32_bf16(
              af[fi][ks], bfr[fj][ks], acc[fi][fj], 0, 0, 0);
    asm volatile("s_waitcnt lgkmcnt(0)" ::: "memory");
    __builtin_amdgcn_sched_barrier(0);
    __builtin_amdgcn_s_barrier();
  }
#pragma unroll
  for (int fi = 0; fi < 4; ++fi)
#pragma unroll
    for (int fj = 0; fj < 4; ++fj) {
      const int col = n0 + wc + (fj << 4) + rr;
#pragma unroll
      for (int r = 0; r < 4; ++r) {
        const int rl = wr + (fi << 4) + (kgl << 2) + r;
        float v = acc[fi][fj][r];
        if (op.act) v = 0.5f * v * (1.0f + erff(v * 0.70710678118654752f));
        if (op.ep == 0) {
          op.outb[(size_t)(lr0 + rl) * F + col] = f2bf(v);
        } else if (op.ep == 1) {
          const size_t off = (size_t)(lr0 + rl) * F + col;
          const float sv = v / (1.0f + __expf(-v));
          op.outb[off] = f2bf(sv * bf2f(op.other[off]));
        } else {
          const int tok = idxP[m0p + rl];
          if (tok >= 0 && col >= MPROT)
            atomicAdd(&outp[(size_t)tok * DIM + col], wts[(size_t)tok * 4 + e] * v);
        }
      }
    }
}

// ---------------- fp16x2 split GEMM (3-term), single-buffer LDS ----------------
// EP: 1 = masked atomicAdd into prefilled outf, K-split via blockIdx.z
// EP: 3 = fused QKV epilogue with fused qk-norm
template <int EP>
__global__ __launch_bounds__(256, 4) void gemm_split_k(
    const _Float16* __restrict__ Ah, const _Float16* __restrict__ Al,
    const _Float16* __restrict__ Bh, const _Float16* __restrict__ Bl,
    int K, int F,
    _Float16* __restrict__ Oh, _Float16* __restrict__ Ol, float oscale,
    float* __restrict__ outf,
    _Float16* __restrict__ K2h, _Float16* __restrict__ K2l,
    _Float16* __restrict__ V2h, _Float16* __restrict__ V2l,
    const float* __restrict__ qnw, const float* __restrict__ knw) {
  __shared__ _Float16 AsH[128][32], AsL[128][32];
  __shared__ _Float16 BsH[128][32], BsL[128][32];
  const int tid = threadIdx.x;
  const int w = tid >> 6, lane = tid & 63;
  const int wr = ((w >> 1) << 6), wc = ((w & 1) << 6);
  int m0, n0;
  tile_swz(m0, n0);
  const int rr = lane & 15, kgl = lane >> 4;
  const int srow = tid >> 2, sslot = tid & 3;

  f32x4 acc[4][4];
#pragma unroll
  for (int a_ = 0; a_ < 4; ++a_)
#pragma unroll
    for (int b_ = 0; b_ < 4; ++b_) acc[a_][b_] = (f32x4){0.f, 0.f, 0.f, 0.f};

  int kt0 = 0, ktN = K >> 5;
  if (EP == 1) { const int hgt = ktN >> 1; kt0 = blockIdx.z * hgt; ktN = kt0 + hgt; }
  for (int kt = kt0; kt < ktN; ++kt) {
    const int k0 = kt << 5;
#pragma unroll
    for (int i = 0; i < 2; ++i) {
      const int r = (i << 6) + srow;
      const int ls = sslot ^ ((r >> 1) & 3);
      const size_t ga = (size_t)(m0 + r) * K + k0 + (ls << 3);
      const size_t gb = (size_t)(n0 + r) * K + k0 + (ls << 3);
      const int lr = (i << 6) + (w << 4);
      gload16(&AsH[lr][0], Ah + ga);
      gload16(&AsL[lr][0], Al + ga);
      gload16(&BsH[lr][0], Bh + gb);
      gload16(&BsL[lr][0], Bl + gb);
    }
    __syncthreads();
    half8 ah[4], al[4], bh[4], bl[4];
#pragma unroll
    for (int f = 0; f < 4; ++f) {
      const int row = wr + (f << 4) + rr;
      const int pa = (kgl ^ ((row >> 1) & 3)) << 3;
      ah[f] = *(const half8*)&AsH[row][pa];
      al[f] = *(const half8*)&AsL[row][pa];
      const int col = wc + (f << 4) + rr;
      const int pb = (kgl ^ ((col >> 1) & 3)) << 3;
      bh[f] = *(const half8*)&BsH[col][pb];
      bl[f] = *(const half8*)&BsL[col][pb];
    }
#pragma unroll
    for (int fi = 0; fi < 4; ++fi)
#pragma unroll
      for (int fj = 0; fj < 4; ++fj) {
        acc[fi][fj] = __builtin_amdgcn_mfma_f32_16x16x32_f16(ah[fi], bh[fj], acc[fi][fj], 0, 0, 0);
        acc[fi][fj] = __builtin_amdgcn_mfma_f32_16x16x32_f16(ah[fi], bl[fj], acc[fi][fj], 0, 0, 0);
        acc[fi][fj] = __builtin_amdgcn_mfma_f32_16x16x32_f16(al[fi], bh[fj], acc[fi][fj], 0, 0, 0);
      }
    __syncthreads();
  }

  if (EP == 3 && n0 < 2048) {
    const bool isq = (n0 < 1024);
    _Float16* ph = isq ? Oh : K2h;
    _Float16* pl = isq ? Ol : K2l;
    const float* wvec = isq ? qnw : knw;
    float wreg[4];
#pragma unroll
    for (int fj = 0; fj < 4; ++fj) wreg[fj] = wvec[(fj << 4) + rr];
#pragma unroll
    for (int fi = 0; fi < 4; ++fi) {
#pragma unroll
      for (int r = 0; r < 4; ++r) {
        float vv[4]; float ss = 0.f;
#pragma unroll
        for (int fj = 0; fj < 4; ++fj) {
          vv[fj] = acc[fi][fj][r] * oscale;
          ss += vv[fj] * vv[fj];
        }
        ss += __shfl_xor(ss, 1);
        ss += __shfl_xor(ss, 2);
        ss += __shfl_xor(ss, 4);
        ss += __shfl_xor(ss, 8);
        const float sc = rsqrtf(ss * (1.0f / (64.0f * SA * SA)) + EPSR);
        const int row = m0 + wr + (fi << 4) + (kgl << 2) + r;
#pragma unroll
        for (int fj = 0; fj < 4; ++fj) {
          const int c = (n0 + wc + (fj << 4) + rr) & 1023;
          const float nv = vv[fj] * sc * wreg[fj];
          const _Float16 hh2 = (_Float16)nv;
          const size_t off = (size_t)row * DIM + c;
          ph[off] = hh2; pl[off] = (_Float16)(nv - (float)hh2);
        }
      }
    }
    return;
  }

#pragma unroll
  for (int fi = 0; fi < 4; ++fi)
#pragma unroll
    for (int fj = 0; fj < 4; ++fj) {
      const int col = n0 + wc + (fj << 4) + rr;
      const int rowb = m0 + wr + (fi << 4) + (kgl << 2);
      if (EP == 3) {
        const int c2 = col - 2048;
        half4 h4, l4;
#pragma unroll
        for (int r = 0; r < 4; ++r) {
          const float v = acc[fi][fj][r] * oscale;
          const _Float16 hh2 = (_Float16)v;
          h4[r] = hh2; l4[r] = (_Float16)(v - (float)hh2);
        }
        const size_t vt = ((size_t)((rowb >> 10) << 4) + (size_t)(c2 >> 6)) * 65536 +
                          (size_t)(c2 & 63) * 1024 + (size_t)(rowb & 1023);
        *(half4*)&V2h[vt] = h4;
        *(half4*)&V2l[vt] = l4;
      } else {
        if (col >= MPROT) {
#pragma unroll
          for (int r = 0; r < 4; ++r) {
            const size_t off = (size_t)(rowb + r) * F + col;
            atomicAdd(&outf[off], acc[fi][fj][r] * oscale);
          }
        }
      }
    }
}

// ---------------- flash attention, causal, fp16x2 split, swapped-QK ----------------
__global__ __launch_bounds__(256, 2) void attn_k(
    const _Float16* __restrict__ Qh, const _Float16* __restrict__ Ql,
    const _Float16* __restrict__ Kh, const _Float16* __restrict__ Kl,
    const _Float16* __restrict__ Vth, const _Float16* __restrict__ Vtl,
    _Float16* __restrict__ Oh, _Float16* __restrict__ Ol) {
  __shared__ _Float16 Ksh[2][32][64], Ksl[2][32][64];
  __shared__ _Float16 Vsh[2][64][40], Vsl[2][64][40];
  __shared__ _Float16 Plh[4][16][40], Pll[4][16][40];
  const int n = blockIdx.x;
  const int j = n >> 1, s = n & 1;
  const int pt = j >> 6;
  const int qt = s ? (7 - pt) : pt;
  const int bh = j & 63;
  const int b = bh >> 4, h = bh & 15;
  const int tid = threadIdx.x, w = tid >> 6, lane = tid & 63;
  const int rr = lane & 15, rg = lane >> 4;
  const size_t tokbase = (size_t)b * TSEQ;
  const int hcol = h << 6;
  const size_t vtbase = (size_t)bh << 16;
  const int q0w = (qt << 7) + (w << 5);
  const float sscale = 0.125f / (SA * SA);

  half8 qfh[2][2], qfl[2][2];
#pragma unroll
  for (int qf = 0; qf < 2; ++qf)
#pragma unroll
    for (int ks = 0; ks < 2; ++ks) {
      const size_t off = (tokbase + q0w + (qf << 4) + rr) * DIM + hcol + (ks << 5) + (rg << 3);
      qfh[qf][ks] = *(const half8*)&Qh[off];
      qfl[qf][ks] = *(const half8*)&Ql[off];
    }

  f32x4 oacc[2][4];
#pragma unroll
  for (int qf = 0; qf < 2; ++qf)
#pragma unroll
    for (int dg = 0; dg < 4; ++dg) oacc[qf][dg] = (f32x4){0.f, 0.f, 0.f, 0.f};
  float mreg[2] = {-INFINITY, -INFINITY}, lreg[2] = {0.f, 0.f};

  const int kr = (w << 3) + (lane >> 3);
  const int kswz = ((lane & 7) ^ (kr & 7)) << 3;
  const int vr = tid >> 2;
  const int vs = (tid & 3) << 3;

  const int ntiles = (qt + 1) << 2;

  {
    gload16(&Ksh[0][w << 3][0], &Kh[(tokbase + kr) * DIM + hcol + kswz]);
    gload16(&Ksl[0][w << 3][0], &Kl[(tokbase + kr) * DIM + hcol + kswz]);
    const half8 vvh = *(const half8*)&Vth[vtbase + (size_t)vr * TSEQ + vs];
    const half8 vvl = *(const half8*)&Vtl[vtbase + (size_t)vr * TSEQ + vs];
    *(half8*)&Vsh[0][vr][vs] = vvh;
    *(half8*)&Vsl[0][vr][vs] = vvl;
    __syncthreads();
  }

  for (int t = 0; t < ntiles; ++t) {
    const int cur = t & 1;
    const int kv0 = t << 5;
    const bool havenext = (t + 1 < ntiles);
    half8 nvh, nvl;
    if (havenext) {
      const int kn = kv0 + 32;
      gload16(&Ksh[cur ^ 1][w << 3][0], &Kh[(tokbase + kn + kr) * DIM + hcol + kswz]);
      gload16(&Ksl[cur ^ 1][w << 3][0], &Kl[(tokbase + kn + kr) * DIM + hcol + kswz]);
      nvh = *(const half8*)&Vth[vtbase + (size_t)vr * TSEQ + kn + vs];
      nvl = *(const half8*)&Vtl[vtbase + (size_t)vr * TSEQ + kn + vs];
    }
    if (kv0 <= q0w + 31) {
      half8 kfh[2][2], kfl[2][2];
#pragma unroll
      for (int kt = 0; kt < 2; ++kt)
#pragma unroll
        for (int ks = 0; ks < 2; ++ks) {
          const int row = (kt << 4) + rr;
          const int sw = ((((ks << 2) + rg)) ^ (row & 7)) << 3;
          kfh[kt][ks] = *(const half8*)&Ksh[cur][row][sw];
          kfl[kt][ks] = *(const half8*)&Ksl[cur][row][sw];
        }
#pragma unroll
      for (int qf = 0; qf < 2; ++qf) {
        if (kv0 > q0w + (qf << 4) + 15) continue;
        f32x4 st[2];
        st[0] = (f32x4){0.f, 0.f, 0.f, 0.f};
        st[1] = (f32x4){0.f, 0.f, 0.f, 0.f};
        __builtin_amdgcn_s_setprio(1);
#pragma unroll
        for (int kt = 0; kt < 2; ++kt)
#pragma unroll
          for (int ks = 0; ks < 2; ++ks) {
            st[kt] = __builtin_amdgcn_mfma_f32_16x16x32_f16(kfh[kt][ks], qfh[qf][ks], st[kt], 0, 0, 0);
            st[kt] = __builtin_amdgcn_mfma_f32_16x16x32_f16(kfh[kt][ks], qfl[qf][ks], st[kt], 0, 0, 0);
            st[kt] = __builtin_amdgcn_mfma_f32_16x16x32_f16(kfl[kt][ks], qfh[qf][ks], st[kt], 0, 0, 0);
          }
        __builtin_amdgcn_s_setprio(0);
        const int qg = q0w + (qf << 4) + rr;
        float s2[2][4]; float mx = -INFINITY;
#pragma unroll
        for (int kt = 0; kt < 2; ++kt)
#pragma unroll
          for (int r = 0; r < 4; ++r) {
            float sv = st[kt][r] * sscale;
            if (kv0 + (kt << 4) + (rg << 2) + r > qg) sv = -INFINITY;
            s2[kt][r] = sv; mx = fmaxf(mx, sv);
          }
        mx = fmaxf(mx, __shfl_xor(mx, 16));
        mx = fmaxf(mx, __shfl_xor(mx, 32));
        const float mn = fmaxf(mreg[qf], mx);
        const float al = __expf(mreg[qf] - mn);
        mreg[qf] = mn;
        float p[2][4]; float rs = 0.f;
#pragma unroll
        for (int kt = 0; kt < 2; ++kt)
#pragma unroll
          for (int r = 0; r < 4; ++r) { p[kt][r] = __expf(s2[kt][r] - mn); rs += p[kt][r]; }
        rs += __shfl_xor(rs, 16);
        rs += __shfl_xor(rs, 32);
        lreg[qf] = lreg[qf] * al + rs;
#pragma unroll
        for (int kt = 0; kt < 2; ++kt) {
          half4 h4, l4;
#pragma unroll
          for (int r = 0; r < 4; ++r) {
            const float pv = p[kt][r] * SPC;
            const _Float16 ph = (_Float16)pv;
            h4[r] = ph; l4[r] = (_Float16)(pv - (float)ph);
          }
          *(half4*)&Plh[w][rr][(kt << 4) + (rg << 2)] = h4;
          *(half4*)&Pll[w][rr][(kt << 4) + (rg << 2)] = l4;
        }
        float alr[4];
#pragma unroll
        for (int r = 0; r < 4; ++r) alr[r] = __shfl(al, (lane & 48) | ((rg << 2) + r));
#pragma unroll
        for (int dg = 0; dg < 4; ++dg)
#pragma unroll
          for (int r = 0; r < 4; ++r) oacc[qf][dg][r] *= alr[r];
        const half8 pah = *(const half8*)&Plh[w][rr][rg << 3];
        const half8 pal = *(const half8*)&Pll[w][rr][rg << 3];
        __builtin_amdgcn_s_setprio(1);
#pragma unroll
        for (int dg = 0; dg < 4; ++dg) {
          const half8 vfh2 = *(const half8*)&Vsh[cur][(dg << 4) + rr][rg << 3];
          const half8 vfl2 = *(const half8*)&Vsl[cur][(dg << 4) + rr][rg << 3];
          oacc[qf][dg] = __builtin_amdgcn_mfma_f32_16x16x32_f16(pah, vfh2, oacc[qf][dg], 0, 0, 0);
          oacc[qf][dg] = __builtin_amdgcn_mfma_f32_16x16x32_f16(pah, vfl2, oacc[qf][dg], 0, 0, 0);
          oacc[qf][dg] = __builtin_amdgcn_mfma_f32_16x16x32_f16(pal, vfh2, oacc[qf][dg], 0, 0, 0);
        }
        __builtin_amdgcn_s_setprio(0);
      }
    }
    if (havenext) {
      *(half8*)&Vsh[cur ^ 1][vr][vs] = nvh;
      *(half8*)&Vsl[cur ^ 1][vr][vs] = nvl;
    }
    __syncthreads();
  }
#pragma unroll
  for (int qf = 0; qf < 2; ++qf) {
    float li[4];
#pragma unroll
    for (int r = 0; r < 4; ++r)
      li[r] = __shfl(lreg[qf], (lane & 48) | ((rg << 2) + r));
#pragma unroll
    for (int dg = 0; dg < 4; ++dg)
#pragma unroll
      for (int r = 0; r < 4; ++r) {
        const int qloc = (rg << 2) + r;
        const float ov = oacc[qf][dg][r] / (li[r] * SPC);
        const _Float16 hh2 = (_Float16)ov;
        const size_t off = (tokbase + q0w + (qf << 4) + qloc) * DIM + hcol + (dg << 4) + rr;
        Oh[off] = hh2;
        Ol[off] = (_Float16)(ov - (float)hh2);
      }
  }
}

extern "C" void kernel_launch(void* const* d_in, const int* in_sizes, int n_in,
                              void* d_out, int out_size, void* d_ws, size_t ws_size,
                              hipStream_t stream) {
  (void)in_sizes; (void)n_in; (void)out_size; (void)ws_size;
  const float* x    = (const float*)d_in[0];
  const float* n1w  = (const float*)d_in[1];
  const float* n2w  = (const float*)d_in[2];
  const float* wq   = (const float*)d_in[3];
  const float* wk   = (const float*)d_in[4];
  const float* wv   = (const float*)d_in[5];
  const float* wo   = (const float*)d_in[6];
  const float* qnw  = (const float*)d_in[7];
  const float* knw  = (const float*)d_in[8];
  const float* gw   = (const float*)d_in[9];
  const float* moesrc[12] = {
    (const float*)d_in[10], (const float*)d_in[11],
    (const float*)d_in[12], (const float*)d_in[13], (const float*)d_in[14],
    (const float*)d_in[15], (const float*)d_in[16], (const float*)d_in[17], (const float*)d_in[18],
    (const float*)d_in[19], (const float*)d_in[20], (const float*)d_in[21]
  };
  float* outp = (float*)d_out;

  char* p = (char*)d_ws;
  auto alloc = [&](size_t bytes) { void* r = (void*)p; p += (bytes + 255) & ~(size_t)255; return r; };
  const size_t NC = (size_t)NTOK * DIM;
  _Float16* hh = (_Float16*)alloc(NC * 2);
  _Float16* hl = (_Float16*)alloc(NC * 2);
  _Float16* qh = (_Float16*)alloc(NC * 2);   // qh..vtl reused as MoE arena
  _Float16* ql = (_Float16*)alloc(NC * 2);
  _Float16* kh = (_Float16*)alloc(NC * 2);
  _Float16* kl = (_Float16*)alloc(NC * 2);
  _Float16* vth = (_Float16*)alloc(NC * 2);
  _Float16* vtl = (_Float16*)alloc(NC * 2);
  unsigned short* xfb = (unsigned short*)alloc(NC * 2);
  float* wts = (float*)alloc((size_t)NTOK * 4 * 4);
  _Float16* awh = (_Float16*)alloc((size_t)4 * 1024 * 1024 * 2);
  _Float16* awl = (_Float16*)alloc((size_t)4 * 1024 * 1024 * 2);
  unsigned short* moeW = (unsigned short*)alloc((size_t)28311552 * 2);
  int* idxP = (int*)alloc((size_t)9216 * 4);
  int* meta = (int*)alloc(512);
  int* work = (int*)alloc((size_t)4 * 8 * MAXI * 4);
  unsigned short* e0t = (unsigned short*)qh;    // 16 MB (qh+ql)
  unsigned short* e1a = (unsigned short*)kh;    // 16 MB (kh+kl)
  unsigned short* e2a = (unsigned short*)vth;   // 16 MB (vth+vtl), reused as e2c
  unsigned short* e1b = (unsigned short*)alloc((size_t)NTOK * 2048 * 2);
  unsigned short* e2b = (unsigned short*)alloc((size_t)NTOK * 2048 * 2);
  unsigned short* e3a = (unsigned short*)alloc((size_t)NTOK * 1024 * 2);
  unsigned short* e3b = (unsigned short*)alloc((size_t)NTOK * 2048 * 2);
  unsigned short* e2c = e2a;

  const size_t moff[12] = {0, 2097152, 4194304, 6291456, 8388608, 10485760,
                           12582912, 16777216, 20971520, 23068672, 24117248, 26214400};
  auto mw = [&](int i) -> const unsigned short* { return moeW + moff[i]; };

  // ---- weight conversions ----
  cvt_attn4_k<<<dim3(1024, 4), dim3(256), 0, stream>>>(wq, wk, wv, wo, awh, awl);
  cvt_moe_all_k<<<dim3(4096, 12), dim3(256), 0, stream>>>(
      moesrc[0], moesrc[1], moesrc[2], moesrc[3], moesrc[4], moesrc[5],
      moesrc[6], moesrc[7], moesrc[8], moesrc[9], moesrc[10], moesrc[11], moeW);
  const _Float16* woh = awh + (3 << 20); const _Float16* wol = awl + (3 << 20);

  // ---- attention path (fp16x2) ----
  rms_split_k<<<dim3(NTOK), dim3(256), 0, stream>>>(x, n1w, hh, hl);
  gemm_split_k<3><<<dim3(24, 32), dim3(256), 0, stream>>>(
      hh, hl, awh, awl, 1024, 3072, qh, ql, 1.0f / SW, nullptr,
      kh, kl, vth, vtl, qnw, knw);
  attn_k<<<dim3(512), dim3(256), 0, stream>>>(qh, ql, kh, kl, vth, vtl, hh, hl);
  hipMemcpyAsync(outp, x, NC * sizeof(float), hipMemcpyDeviceToDevice, stream);
  gemm_split_k<1><<<dim3(8, 32, 2), dim3(256), 0, stream>>>(
      hh, hl, woh, wol, 1024, 1024, nullptr, nullptr, 1.0f / (SA * SW), outp,
      nullptr, nullptr, nullptr, nullptr, nullptr, nullptr);

  // ---- MoE (sparse top-2, dense work-list phases, scatter into outp) ----
  rmsgate_k<<<dim3(NTOK), dim3(256), 0, stream>>>(outp, n2w, gw, xfb, wts);

  MoeCfg cfg;
  const int nbn_tab[4][4] = {{16, 16, 16, 8},
                             {8, 16, 16, 0},
                             {0, 8, 16, 16},
                             {0, 0, 8, 8}};
  const int ks_tab[4][4]  = {{1, 1, 1, 1},
                             {2, 1, 1, 1},
                             {1, 2, 1, 1},
                             {1, 1, 4, 2}};
  for (int pp = 0; pp < 4; ++pp)
    for (int ee = 0; ee < 4; ++ee) { cfg.nbn[pp][ee] = nbn_tab[pp][ee]; cfg.ks[pp][ee] = ks_tab[pp][ee]; }

  route2_k<<<dim3(1), dim3(256), 0, stream>>>(wts, idxP, meta, work, cfg);

  auto mk = [&](const unsigned short* A, const unsigned short* B, unsigned short* outb,
                const unsigned short* other, int K, int nbn, int act, int ep, int gath, int ks) {
    SubOpP s; s.A = A; s.Bw = B; s.outb = outb; s.other = other;
    s.K = K; s.nbn = nbn; s.act = act; s.ep = ep; s.gath = gath; s.ks = ks;
    return s;
  };
  const SubOpP none = mk(nullptr, nullptr, nullptr, nullptr, 1024, 0, 0, 0, 0, 1);

  PhaseP p1;
  p1.op[0] = mk(xfb, mw(0), e0t, nullptr, 1024, 16, 1, 0, 1, 1);  // e0: gelu(x@up)
  p1.op[1] = mk(xfb, mw(3), e1a, nullptr, 1024, 16, 0, 0, 1, 1);  // e1: x@w2 raw
  p1.op[2] = mk(xfb, mw(5), e2a, nullptr, 1024, 16, 1, 0, 1, 1);  // e2: gelu(x@l1)
  p1.op[3] = mk(xfb, mw(9), e3a, nullptr, 1024, 8, 1, 0, 1, 1);   // e3: gelu(x@dn)
  gemm_moe_k<<<dim3(8, MAXI), dim3(256), 0, stream>>>(p1, meta, idxP, wts, outp, work);

  PhaseP p2;
  p2.op[0] = mk(e0t, mw(1), nullptr, nullptr, 2048, 8, 0, 2, 0, 2);  // e0 down -> outp
  p2.op[1] = mk(xfb, mw(2), e1b, e1a, 1024, 16, 0, 1, 1, 1);         // e1: silu(x@w1)*e1a
  p2.op[2] = mk(e2a, mw(6), e2b, nullptr, 2048, 16, 1, 0, 0, 1);     // e2: gelu(@l2)
  p2.op[3] = none;
  gemm_moe_k<<<dim3(8, MAXI), dim3(256), 0, stream>>>(p2, meta, idxP, wts, outp, work + 8 * MAXI);

  PhaseP p3;
  p3.op[0] = none;
  p3.op[1] = mk(e1b, mw(4), nullptr, nullptr, 2048, 8, 0, 2, 0, 2);  // e1 down -> outp
  p3.op[2] = mk(e2b, mw(7), e2c, nullptr, 2048, 16, 1, 0, 0, 1);     // e2: gelu(@l3)
  p3.op[3] = mk(e3a, mw(10), e3b, nullptr, 1024, 16, 1, 0, 0, 1);    // e3: gelu(@up)
  gemm_moe_k<<<dim3(8, MAXI), dim3(256), 0, stream>>>(p3, meta, idxP, wts, outp, work + 16 * MAXI);

  PhaseP p4;
  p4.op[0] = none;
  p4.op[1] = none;
  p4.op[2] = mk(e2c, mw(8), nullptr, nullptr, 2048, 8, 0, 2, 0, 4);  // e2 l4 -> outp (ks4)
  p4.op[3] = mk(e3b, mw(11), nullptr, nullptr, 2048, 8, 0, 2, 0, 2); // e3 out -> outp (ks2)
  gemm_moe_k<<<dim3(8, MAXI), dim3(256), 0, stream>>>(p4, meta, idxP, wts, outp, work + 24 * MAXI);
}

// Round 13
// 597.701 us; speedup vs baseline: 1.1737x; 1.1737x over previous
//
#include <hip/hip_runtime.h>
#include <math.h>

#define DIM   1024
#define NTOK  4096
#define TSEQ  1024
#define NHEAD 16
#define MPROT 256
#define EPSR  1.1920929e-07f
#define SA    64.0f
#define SW    256.0f
#define SPC   64.0f
#define MAXI  160

typedef __attribute__((ext_vector_type(8))) short          short8;
typedef __attribute__((ext_vector_type(8))) _Float16       half8;
typedef __attribute__((ext_vector_type(4))) _Float16       half4;
typedef __attribute__((ext_vector_type(4))) float          f32x4;
typedef __attribute__((ext_vector_type(4))) unsigned short us4;

static __device__ __forceinline__ float bf2f(unsigned short s) {
  union { unsigned int u; float f; } c; c.u = ((unsigned int)s) << 16; return c.f;
}
static __device__ __forceinline__ unsigned short f2bf(float f) {
  union { float f; unsigned int u; } c; c.f = f;
  return (unsigned short)((c.u + 0x7fffu + ((c.u >> 16) & 1u)) >> 16);
}
static __device__ __forceinline__ void gload16(void* lds, const void* g) {
  __builtin_amdgcn_global_load_lds(
      (__attribute__((address_space(1))) void*)const_cast<void*>(g),
      (__attribute__((address_space(3))) void*)lds, 16, 0, 0);
}

// XCD swizzle for dense split-GEMMs: stripe m-blocks across XCDs.
static __device__ __forceinline__ void tile_swz(int& m0, int& n0) {
  const int gx = gridDim.x;
  const int L = blockIdx.y * gx + blockIdx.x;
  const int xcd = L & 7;
  const int j = L >> 3;
  const int mbq = j / gx;
  const int nb = j - mbq * gx;
  m0 = ((mbq << 3) | xcd) << 7;
  n0 = nb << 7;
}

// ---------------- conversions ----------------
__global__ __launch_bounds__(256) void cvt_attn4_k(const float* __restrict__ wq,
                                                   const float* __restrict__ wk,
                                                   const float* __restrict__ wv,
                                                   const float* __restrict__ wo,
                                                   _Float16* __restrict__ dh,
                                                   _Float16* __restrict__ dl) {
  const int wi = blockIdx.y;
  const float* s = (wi == 0) ? wq : (wi == 1) ? wk : (wi == 2) ? wv : wo;
  const int i = blockIdx.x * 256 + threadIdx.x;
  const size_t off4 = ((size_t)wi << 20) >> 2;
  const float4 v = ((const float4*)s)[i];
  float a0 = v.x * SW, a1 = v.y * SW, a2 = v.z * SW, a3 = v.w * SW;
  half4 hv, lv;
  _Float16 h0 = (_Float16)a0; hv[0] = h0; lv[0] = (_Float16)(a0 - (float)h0);
  _Float16 h1 = (_Float16)a1; hv[1] = h1; lv[1] = (_Float16)(a1 - (float)h1);
  _Float16 h2 = (_Float16)a2; hv[2] = h2; lv[2] = (_Float16)(a2 - (float)h2);
  _Float16 h3 = (_Float16)a3; hv[3] = h3; lv[3] = (_Float16)(a3 - (float)h3);
  ((half4*)dh)[off4 + i] = hv; ((half4*)dl)[off4 + i] = lv;
}

__global__ __launch_bounds__(256) void cvt_moe_all_k(
    const float* s0, const float* s1, const float* s2, const float* s3,
    const float* s4, const float* s5, const float* s6, const float* s7,
    const float* s8, const float* s9, const float* s10, const float* s11,
    unsigned short* __restrict__ dst) {
  const int n4tab[12] = {524288, 524288, 524288, 524288, 524288, 524288,
                         1048576, 1048576, 524288, 262144, 524288, 524288};
  const size_t offtab[12] = {0, 2097152, 4194304, 6291456, 8388608, 10485760,
                             12582912, 16777216, 20971520, 23068672, 24117248, 26214400};
  const int wi = blockIdx.y;
  const int i = blockIdx.x * 256 + threadIdx.x;
  if (i >= n4tab[wi]) return;
  const float* s;
  switch (wi) {
    case 0: s = s0; break; case 1: s = s1; break; case 2: s = s2; break;
    case 3: s = s3; break; case 4: s = s4; break; case 5: s = s5; break;
    case 6: s = s6; break; case 7: s = s7; break; case 8: s = s8; break;
    case 9: s = s9; break; case 10: s = s10; break; default: s = s11; break;
  }
  const float4 v = ((const float4*)s)[i];
  us4 o; o[0] = f2bf(v.x); o[1] = f2bf(v.y); o[2] = f2bf(v.z); o[3] = f2bf(v.w);
  ((us4*)(dst + offtab[wi]))[i] = o;
}

// ---------------- RMS norms ----------------
__global__ __launch_bounds__(256) void rms_split_k(const float* __restrict__ in,
                                                   const float* __restrict__ wgt,
                                                   _Float16* __restrict__ oh,
                                                   _Float16* __restrict__ ol) {
  const int row = blockIdx.x, tid = threadIdx.x;
  const float4 v = ((const float4*)(in + (size_t)row * DIM))[tid];
  float ss = v.x * v.x + v.y * v.y + v.z * v.z + v.w * v.w;
#pragma unroll
  for (int o = 32; o; o >>= 1) ss += __shfl_xor(ss, o);
  __shared__ float red[4];
  if ((tid & 63) == 0) red[tid >> 6] = ss;
  __syncthreads();
  const float sc = rsqrtf((red[0] + red[1] + red[2] + red[3]) * (1.0f / DIM) + EPSR) * SA;
  const float4 wv = ((const float4*)wgt)[tid];
  float a[4] = {v.x * sc * wv.x, v.y * sc * wv.y, v.z * sc * wv.z, v.w * sc * wv.w};
  half4 hv, lv;
#pragma unroll
  for (int j = 0; j < 4; ++j) {
    _Float16 hh = (_Float16)a[j]; hv[j] = hh; lv[j] = (_Float16)(a[j] - (float)hh);
  }
  ((half4*)(oh + (size_t)row * DIM))[tid] = hv;
  ((half4*)(ol + (size_t)row * DIM))[tid] = lv;
}

// fused RMSNorm(bf16 out) + gate logits/softmax/top-2
__global__ __launch_bounds__(256) void rmsgate_k(const float* __restrict__ x2,
                                                 const float* __restrict__ n2w,
                                                 const float* __restrict__ gw,
                                                 unsigned short* __restrict__ xfb,
                                                 float* __restrict__ wts) {
  const int row = blockIdx.x, tid = threadIdx.x;
  const float4 v = ((const float4*)(x2 + (size_t)row * DIM))[tid];
  float ss = v.x * v.x + v.y * v.y + v.z * v.z + v.w * v.w;
#pragma unroll
  for (int o = 32; o; o >>= 1) ss += __shfl_xor(ss, o);
  __shared__ float red[4];
  __shared__ float redE[4][4];
  const int w = tid >> 6, lane = tid & 63;
  if (lane == 0) red[w] = ss;
  __syncthreads();
  const float sc = rsqrtf((red[0] + red[1] + red[2] + red[3]) * (1.0f / DIM) + EPSR);
  const float4 nw = ((const float4*)n2w)[tid];
  const float xn0 = v.x * sc * nw.x, xn1 = v.y * sc * nw.y;
  const float xn2 = v.z * sc * nw.z, xn3 = v.w * sc * nw.w;
  us4 ob; ob[0] = f2bf(xn0); ob[1] = f2bf(xn1); ob[2] = f2bf(xn2); ob[3] = f2bf(xn3);
  ((us4*)(xfb + (size_t)row * DIM))[tid] = ob;
#pragma unroll
  for (int e = 0; e < 4; ++e) {
    const float4 g = ((const float4*)(gw + (size_t)e * DIM))[tid];
    float d = xn0 * g.x + xn1 * g.y + xn2 * g.z + xn3 * g.w;
#pragma unroll
    for (int o = 32; o; o >>= 1) d += __shfl_xor(d, o);
    if (lane == 0) redE[w][e] = d;
  }
  __syncthreads();
  if (tid == 0) {
    float lg[4];
#pragma unroll
    for (int e = 0; e < 4; ++e) lg[e] = redE[0][e] + redE[1][e] + redE[2][e] + redE[3][e];
    const float mx = fmaxf(fmaxf(lg[0], lg[1]), fmaxf(lg[2], lg[3]));
    float pe[4]; float sum = 0.0f;
#pragma unroll
    for (int e = 0; e < 4; ++e) { pe[e] = __expf(lg[e] - mx); sum += pe[e]; }
#pragma unroll
    for (int e = 0; e < 4; ++e) pe[e] /= sum;
    int i1 = 0;
    for (int e = 1; e < 4; ++e) if (pe[e] > pe[i1]) i1 = e;
    int i2 = -1;
    for (int e = 0; e < 4; ++e) { if (e == i1) continue; if (i2 < 0 || pe[e] > pe[i2]) i2 = e; }
    const float s2 = pe[i1] + pe[i2] + 1e-8f;
    float o[4] = {0.f, 0.f, 0.f, 0.f};
    o[i1] = pe[i1] / s2; o[i2] = pe[i2] / s2;
    float4 r; r.x = o[0]; r.y = o[1]; r.z = o[2]; r.w = o[3];
    *(float4*)(wts + (size_t)row * 4) = r;
  }
}

// ---------------- routing + dense per-XCD work lists ----------------
struct MoeCfg { int nbn[4][4]; int ks[4][4]; };

__global__ __launch_bounds__(256) void route2_k(const float* __restrict__ wts,
                                                int* __restrict__ idxP,
                                                int* __restrict__ meta,
                                                int* __restrict__ work,
                                                MoeCfg cfg) {
  const int tid = threadIdx.x, w = tid >> 6, lane = tid & 63;
  __shared__ int wsum[4];
  __shared__ int baseS;
  int off = 0;
  for (int e = 0; e < 4; ++e) {
    if (tid == 0) baseS = 0;
    __syncthreads();
    for (int c = 0; c < 16; ++c) {
      const int tok = (c << 8) + tid;
      const bool pred = wts[(size_t)tok * 4 + e] > 0.0f;
      const unsigned long long m = __ballot(pred);
      const int lanepre = __popcll(m & ((1ull << lane) - 1ull));
      if (lane == 0) wsum[w] = __popcll(m);
      __syncthreads();
      int wpre = 0;
#pragma unroll
      for (int i = 0; i < 4; ++i) wpre += (i < w) ? wsum[i] : 0;
      const int tot = wsum[0] + wsum[1] + wsum[2] + wsum[3];
      if (pred) idxP[off + baseS + wpre + lanepre] = tok;
      __syncthreads();
      if (tid == 0) baseS += tot;
      __syncthreads();
    }
    const int cnt = baseS;
    const int padded = (cnt + 127) & ~127;
    for (int j = cnt + tid; j < padded; j += 256) idxP[off + j] = -1;
    if (tid == 0) meta[80 + e] = off;
    const int mb0 = off >> 7, nmb = padded >> 7;
    for (int j = tid; j < nmb; j += 256) meta[mb0 + j] = e;
    off += padded;
    __syncthreads();
  }
  for (int j = (off >> 7) + tid; j < 72; j += 256) meta[j] = -1;
  for (int j = tid; j < 4 * 8 * MAXI; j += 256) work[j] = -1;
  __syncthreads();
  if (tid < 32) {
    const int p = tid >> 3, x = tid & 7;
    int* wb = work + p * (8 * MAXI);
    int n = 0;
    const int totmb = off >> 7;
    for (int mb = x; mb < totmb; mb += 8) {
      const int e = meta[mb];
      const int nbn = cfg.nbn[p][e];
      const int ks = cfg.ks[p][e];
      for (int nb = 0; nb < nbn; ++nb)
        for (int k = 0; k < ks; ++k) {
          wb[n * 8 + x] = mb | (nb << 8) | (k << 16);
          ++n;
        }
    }
  }
}

// ---------------- packed grouped sparse bf16 GEMM (single-buffer LDS, work-list) ----------------
struct SubOpP {
  const unsigned short* A;
  const unsigned short* Bw;
  unsigned short* outb;
  const unsigned short* other;
  int K, nbn, act, ep, gath, ks;  // ep: 0 store, 1 silu*other, 2 scatter atomicAdd->outp (masked)
};
struct PhaseP { SubOpP op[4]; };  // indexed by expert

__global__ __launch_bounds__(256, 4) void gemm_moe_k(PhaseP ph,
                                                     const int* __restrict__ meta,
                                                     const int* __restrict__ idxP,
                                                     const float* __restrict__ wts,
                                                     float* __restrict__ outp,
                                                     const int* __restrict__ wk) {
  __shared__ unsigned short As[128][64];
  __shared__ unsigned short Bs[128][64];
  const int item = wk[blockIdx.y * 8 + blockIdx.x];
  if (item < 0) return;
  const int mb = item & 255;
  const int nb = (item >> 8) & 255;
  const int kpart = (item >> 16) & 3;
  const int e = meta[mb];
  SubOpP op;
  switch (e) {
    case 0: op = ph.op[0]; break;
    case 1: op = ph.op[1]; break;
    case 2: op = ph.op[2]; break;
    default: op = ph.op[3]; break;
  }
  const int m0p = mb << 7;
  const int lr0 = m0p - meta[80 + e];
  const int n0 = nb << 7;
  const int F = op.nbn << 7;
  const int K = op.K;
  const int tid = threadIdx.x;
  const int w = tid >> 6, lane = tid & 63;
  const int wr = ((w >> 1) << 6), wc = ((w & 1) << 6);
  const int rr = lane & 15, kgl = lane >> 4;
  const int srow = tid >> 3, sslot = tid & 7;

  int grow[4];
#pragma unroll
  for (int i = 0; i < 4; ++i) {
    const int r = (i << 5) + srow;
    if (op.gath) {
      const int t = idxP[m0p + r];
      grow[i] = (t < 0) ? 0 : t;
    } else {
      grow[i] = lr0 + r;
    }
  }

  f32x4 acc[4][4];
#pragma unroll
  for (int a_ = 0; a_ < 4; ++a_)
#pragma unroll
    for (int b_ = 0; b_ < 4; ++b_) acc[a_][b_] = (f32x4){0.f, 0.f, 0.f, 0.f};

  int kt0 = 0, ktN = K >> 6;
  if (op.ks > 1) { const int seg = ktN / op.ks; kt0 = kpart * seg; ktN = kt0 + seg; }
  for (int kt = kt0; kt < ktN; ++kt) {
    const int k0 = kt << 6;
#pragma unroll
    for (int i = 0; i < 4; ++i) {
      const int r = (i << 5) + srow;
      const int ls = sslot ^ (r & 7);
      gload16(&As[(i << 5) + (w << 3)][0], op.A + (size_t)grow[i] * K + k0 + (ls << 3));
      gload16(&Bs[(i << 5) + (w << 3)][0], op.Bw + (size_t)(n0 + r) * K + k0 + (ls << 3));
    }
    __syncthreads();
    short8 af[4][2], bfr[4][2];
#pragma unroll
    for (int f = 0; f < 4; ++f) {
#pragma unroll
      for (int ks = 0; ks < 2; ++ks) {
        const int row = wr + (f << 4) + rr;
        const int kg = (ks << 2) + kgl;
        af[f][ks] = *(const short8*)&As[row][(kg ^ (row & 7)) << 3];
        const int col = wc + (f << 4) + rr;
        bfr[f][ks] = *(const short8*)&Bs[col][(kg ^ (col & 7)) << 3];
      }
    }
#pragma unroll
    for (int fi = 0; fi < 4; ++fi)
#pragma unroll
      for (int fj = 0; fj < 4; ++fj)
#pragma unroll
        for (int ks = 0; ks < 2; ++ks)
          acc[fi][fj] = __builtin_amdgcn_mfma_f32_16x16x32_bf16(
              af[fi][ks], bfr[fj][ks], acc[fi][fj], 0, 0, 0);
    __syncthreads();
  }
#pragma unroll
  for (int fi = 0; fi < 4; ++fi)
#pragma unroll
    for (int fj = 0; fj < 4; ++fj) {
      const int col = n0 + wc + (fj << 4) + rr;
#pragma unroll
      for (int r = 0; r < 4; ++r) {
        const int rl = wr + (fi << 4) + (kgl << 2) + r;
        float v = acc[fi][fj][r];
        if (op.act) v = 0.5f * v * (1.0f + erff(v * 0.70710678118654752f));
        if (op.ep == 0) {
          op.outb[(size_t)(lr0 + rl) * F + col] = f2bf(v);
        } else if (op.ep == 1) {
          const size_t off = (size_t)(lr0 + rl) * F + col;
          const float sv = v / (1.0f + __expf(-v));
          op.outb[off] = f2bf(sv * bf2f(op.other[off]));
        } else {
          const int tok = idxP[m0p + rl];
          if (tok >= 0 && col >= MPROT)
            atomicAdd(&outp[(size_t)tok * DIM + col], wts[(size_t)tok * 4 + e] * v);
        }
      }
    }
}

// ---------------- fp16x2 split GEMM (3-term), single-buffer LDS ----------------
// EP: 1 = fp32: resid + masked(v); 3 = fused QKV epilogue with fused qk-norm
template <int EP>
__global__ __launch_bounds__(256, 4) void gemm_split_k(
    const _Float16* __restrict__ Ah, const _Float16* __restrict__ Al,
    const _Float16* __restrict__ Bh, const _Float16* __restrict__ Bl,
    int K, int F,
    _Float16* __restrict__ Oh, _Float16* __restrict__ Ol, float oscale,
    const float* __restrict__ resid, float* __restrict__ outf,
    _Float16* __restrict__ K2h, _Float16* __restrict__ K2l,
    _Float16* __restrict__ V2h, _Float16* __restrict__ V2l,
    const float* __restrict__ qnw, const float* __restrict__ knw) {
  __shared__ _Float16 AsH[128][32], AsL[128][32];
  __shared__ _Float16 BsH[128][32], BsL[128][32];
  const int tid = threadIdx.x;
  const int w = tid >> 6, lane = tid & 63;
  const int wr = ((w >> 1) << 6), wc = ((w & 1) << 6);
  int m0, n0;
  tile_swz(m0, n0);
  const int rr = lane & 15, kgl = lane >> 4;
  const int srow = tid >> 2, sslot = tid & 3;

  f32x4 acc[4][4];
#pragma unroll
  for (int a_ = 0; a_ < 4; ++a_)
#pragma unroll
    for (int b_ = 0; b_ < 4; ++b_) acc[a_][b_] = (f32x4){0.f, 0.f, 0.f, 0.f};

  const int KT = K >> 5;
  for (int kt = 0; kt < KT; ++kt) {
    const int k0 = kt << 5;
#pragma unroll
    for (int i = 0; i < 2; ++i) {
      const int r = (i << 6) + srow;
      const int ls = sslot ^ ((r >> 1) & 3);
      const size_t ga = (size_t)(m0 + r) * K + k0 + (ls << 3);
      const size_t gb = (size_t)(n0 + r) * K + k0 + (ls << 3);
      const int lr = (i << 6) + (w << 4);
      gload16(&AsH[lr][0], Ah + ga);
      gload16(&AsL[lr][0], Al + ga);
      gload16(&BsH[lr][0], Bh + gb);
      gload16(&BsL[lr][0], Bl + gb);
    }
    __syncthreads();
    half8 ah[4], al[4], bh[4], bl[4];
#pragma unroll
    for (int f = 0; f < 4; ++f) {
      const int row = wr + (f << 4) + rr;
      const int pa = (kgl ^ ((row >> 1) & 3)) << 3;
      ah[f] = *(const half8*)&AsH[row][pa];
      al[f] = *(const half8*)&AsL[row][pa];
      const int col = wc + (f << 4) + rr;
      const int pb = (kgl ^ ((col >> 1) & 3)) << 3;
      bh[f] = *(const half8*)&BsH[col][pb];
      bl[f] = *(const half8*)&BsL[col][pb];
    }
#pragma unroll
    for (int fi = 0; fi < 4; ++fi)
#pragma unroll
      for (int fj = 0; fj < 4; ++fj) {
        acc[fi][fj] = __builtin_amdgcn_mfma_f32_16x16x32_f16(ah[fi], bh[fj], acc[fi][fj], 0, 0, 0);
        acc[fi][fj] = __builtin_amdgcn_mfma_f32_16x16x32_f16(ah[fi], bl[fj], acc[fi][fj], 0, 0, 0);
        acc[fi][fj] = __builtin_amdgcn_mfma_f32_16x16x32_f16(al[fi], bh[fj], acc[fi][fj], 0, 0, 0);
      }
    __syncthreads();
  }

  if (EP == 3 && n0 < 2048) {
    // q (n0<1024) or k tile: fuse per-(row,head) RMS norm over the 64 head dims.
    const bool isq = (n0 < 1024);
    _Float16* ph = isq ? Oh : K2h;
    _Float16* pl = isq ? Ol : K2l;
    const float* wvec = isq ? qnw : knw;
    float wreg[4];
#pragma unroll
    for (int fj = 0; fj < 4; ++fj) wreg[fj] = wvec[(fj << 4) + rr];
#pragma unroll
    for (int fi = 0; fi < 4; ++fi) {
#pragma unroll
      for (int r = 0; r < 4; ++r) {
        float vv[4]; float ss = 0.f;
#pragma unroll
        for (int fj = 0; fj < 4; ++fj) {
          vv[fj] = acc[fi][fj][r] * oscale;
          ss += vv[fj] * vv[fj];
        }
        ss += __shfl_xor(ss, 1);
        ss += __shfl_xor(ss, 2);
        ss += __shfl_xor(ss, 4);
        ss += __shfl_xor(ss, 8);
        const float sc = rsqrtf(ss * (1.0f / (64.0f * SA * SA)) + EPSR);
        const int row = m0 + wr + (fi << 4) + (kgl << 2) + r;
#pragma unroll
        for (int fj = 0; fj < 4; ++fj) {
          const int c = (n0 + wc + (fj << 4) + rr) & 1023;
          const float nv = vv[fj] * sc * wreg[fj];
          const _Float16 hh2 = (_Float16)nv;
          const size_t off = (size_t)row * DIM + c;
          ph[off] = hh2; pl[off] = (_Float16)(nv - (float)hh2);
        }
      }
    }
    return;
  }

#pragma unroll
  for (int fi = 0; fi < 4; ++fi)
#pragma unroll
    for (int fj = 0; fj < 4; ++fj) {
      const int col = n0 + wc + (fj << 4) + rr;
      const int rowb = m0 + wr + (fi << 4) + (kgl << 2);
      if (EP == 3) {
        const int c2 = col - 2048;
        half4 h4, l4;
#pragma unroll
        for (int r = 0; r < 4; ++r) {
          const float v = acc[fi][fj][r] * oscale;
          const _Float16 hh2 = (_Float16)v;
          h4[r] = hh2; l4[r] = (_Float16)(v - (float)hh2);
        }
        const size_t vt = ((size_t)((rowb >> 10) << 4) + (size_t)(c2 >> 6)) * 65536 +
                          (size_t)(c2 & 63) * 1024 + (size_t)(rowb & 1023);
        *(half4*)&V2h[vt] = h4;
        *(half4*)&V2l[vt] = l4;
      } else {
#pragma unroll
        for (int r = 0; r < 4; ++r) {
          const size_t off = (size_t)(rowb + r) * F + col;
          const float v = acc[fi][fj][r] * oscale;
          outf[off] = resid[off] + (col >= MPROT ? v : 0.0f);
        }
      }
    }
}

// ---------------- flash attention, causal, fp16x2 split, swapped-QK ----------------
// load-balanced qt pairing: blocks 2j/2j+1 get qt = pt / 7-pt (uniform 36 tiles per pair)
__global__ __launch_bounds__(256, 2) void attn_k(
    const _Float16* __restrict__ Qh, const _Float16* __restrict__ Ql,
    const _Float16* __restrict__ Kh, const _Float16* __restrict__ Kl,
    const _Float16* __restrict__ Vth, const _Float16* __restrict__ Vtl,
    _Float16* __restrict__ Oh, _Float16* __restrict__ Ol) {
  __shared__ _Float16 Ksh[2][32][64], Ksl[2][32][64];
  __shared__ _Float16 Vsh[2][64][40], Vsl[2][64][40];
  __shared__ _Float16 Plh[4][16][40], Pll[4][16][40];
  const int n = blockIdx.x;
  const int j = n >> 1, s = n & 1;
  const int pt = j >> 6;
  const int qt = s ? (7 - pt) : pt;
  const int bh = j & 63;
  const int b = bh >> 4, h = bh & 15;
  const int tid = threadIdx.x, w = tid >> 6, lane = tid & 63;
  const int rr = lane & 15, rg = lane >> 4;
  const size_t tokbase = (size_t)b * TSEQ;
  const int hcol = h << 6;
  const size_t vtbase = (size_t)bh << 16;
  const int q0w = (qt << 7) + (w << 5);
  const float sscale = 0.125f / (SA * SA);

  half8 qfh[2][2], qfl[2][2];
#pragma unroll
  for (int qf = 0; qf < 2; ++qf)
#pragma unroll
    for (int ks = 0; ks < 2; ++ks) {
      const size_t off = (tokbase + q0w + (qf << 4) + rr) * DIM + hcol + (ks << 5) + (rg << 3);
      qfh[qf][ks] = *(const half8*)&Qh[off];
      qfl[qf][ks] = *(const half8*)&Ql[off];
    }

  f32x4 oacc[2][4];
#pragma unroll
  for (int qf = 0; qf < 2; ++qf)
#pragma unroll
    for (int dg = 0; dg < 4; ++dg) oacc[qf][dg] = (f32x4){0.f, 0.f, 0.f, 0.f};
  float mreg[2] = {-INFINITY, -INFINITY}, lreg[2] = {0.f, 0.f};

  const int kr = (w << 3) + (lane >> 3);
  const int kswz = ((lane & 7) ^ (kr & 7)) << 3;
  const int vr = tid >> 2;
  const int vs = (tid & 3) << 3;

  const int ntiles = (qt + 1) << 2;

  {
    gload16(&Ksh[0][w << 3][0], &Kh[(tokbase + kr) * DIM + hcol + kswz]);
    gload16(&Ksl[0][w << 3][0], &Kl[(tokbase + kr) * DIM + hcol + kswz]);
    const half8 vvh = *(const half8*)&Vth[vtbase + (size_t)vr * TSEQ + vs];
    const half8 vvl = *(const half8*)&Vtl[vtbase + (size_t)vr * TSEQ + vs];
    *(half8*)&Vsh[0][vr][vs] = vvh;
    *(half8*)&Vsl[0][vr][vs] = vvl;
    __syncthreads();
  }

  for (int t = 0; t < ntiles; ++t) {
    const int cur = t & 1;
    const int kv0 = t << 5;
    const bool havenext = (t + 1 < ntiles);
    half8 nvh, nvl;
    if (havenext) {
      const int kn = kv0 + 32;
      gload16(&Ksh[cur ^ 1][w << 3][0], &Kh[(tokbase + kn + kr) * DIM + hcol + kswz]);
      gload16(&Ksl[cur ^ 1][w << 3][0], &Kl[(tokbase + kn + kr) * DIM + hcol + kswz]);
      nvh = *(const half8*)&Vth[vtbase + (size_t)vr * TSEQ + kn + vs];
      nvl = *(const half8*)&Vtl[vtbase + (size_t)vr * TSEQ + kn + vs];
    }
    if (kv0 <= q0w + 31) {
      half8 kfh[2][2], kfl[2][2];
#pragma unroll
      for (int kt = 0; kt < 2; ++kt)
#pragma unroll
        for (int ks = 0; ks < 2; ++ks) {
          const int row = (kt << 4) + rr;
          const int sw = ((((ks << 2) + rg)) ^ (row & 7)) << 3;
          kfh[kt][ks] = *(const half8*)&Ksh[cur][row][sw];
          kfl[kt][ks] = *(const half8*)&Ksl[cur][row][sw];
        }
#pragma unroll
      for (int qf = 0; qf < 2; ++qf) {
        if (kv0 > q0w + (qf << 4) + 15) continue;
        f32x4 st[2];
        st[0] = (f32x4){0.f, 0.f, 0.f, 0.f};
        st[1] = (f32x4){0.f, 0.f, 0.f, 0.f};
        __builtin_amdgcn_s_setprio(1);
#pragma unroll
        for (int kt = 0; kt < 2; ++kt)
#pragma unroll
          for (int ks = 0; ks < 2; ++ks) {
            st[kt] = __builtin_amdgcn_mfma_f32_16x16x32_f16(kfh[kt][ks], qfh[qf][ks], st[kt], 0, 0, 0);
            st[kt] = __builtin_amdgcn_mfma_f32_16x16x32_f16(kfh[kt][ks], qfl[qf][ks], st[kt], 0, 0, 0);
            st[kt] = __builtin_amdgcn_mfma_f32_16x16x32_f16(kfl[kt][ks], qfh[qf][ks], st[kt], 0, 0, 0);
          }
        __builtin_amdgcn_s_setprio(0);
        const int qg = q0w + (qf << 4) + rr;
        float s2[2][4]; float mx = -INFINITY;
#pragma unroll
        for (int kt = 0; kt < 2; ++kt)
#pragma unroll
          for (int r = 0; r < 4; ++r) {
            float sv = st[kt][r] * sscale;
            if (kv0 + (kt << 4) + (rg << 2) + r > qg) sv = -INFINITY;
            s2[kt][r] = sv; mx = fmaxf(mx, sv);
          }
        mx = fmaxf(mx, __shfl_xor(mx, 16));
        mx = fmaxf(mx, __shfl_xor(mx, 32));
        const float mn = fmaxf(mreg[qf], mx);
        const float al = __expf(mreg[qf] - mn);
        mreg[qf] = mn;
        float p[2][4]; float rs = 0.f;
#pragma unroll
        for (int kt = 0; kt < 2; ++kt)
#pragma unroll
          for (int r = 0; r < 4; ++r) { p[kt][r] = __expf(s2[kt][r] - mn); rs += p[kt][r]; }
        rs += __shfl_xor(rs, 16);
        rs += __shfl_xor(rs, 32);
        lreg[qf] = lreg[qf] * al + rs;
#pragma unroll
        for (int kt = 0; kt < 2; ++kt) {
          half4 h4, l4;
#pragma unroll
          for (int r = 0; r < 4; ++r) {
            const float pv = p[kt][r] * SPC;
            const _Float16 ph = (_Float16)pv;
            h4[r] = ph; l4[r] = (_Float16)(pv - (float)ph);
          }
          *(half4*)&Plh[w][rr][(kt << 4) + (rg << 2)] = h4;
          *(half4*)&Pll[w][rr][(kt << 4) + (rg << 2)] = l4;
        }
        float alr[4];
#pragma unroll
        for (int r = 0; r < 4; ++r) alr[r] = __shfl(al, (lane & 48) | ((rg << 2) + r));
#pragma unroll
        for (int dg = 0; dg < 4; ++dg)
#pragma unroll
          for (int r = 0; r < 4; ++r) oacc[qf][dg][r] *= alr[r];
        const half8 pah = *(const half8*)&Plh[w][rr][rg << 3];
        const half8 pal = *(const half8*)&Pll[w][rr][rg << 3];
        __builtin_amdgcn_s_setprio(1);
#pragma unroll
        for (int dg = 0; dg < 4; ++dg) {
          const half8 vfh2 = *(const half8*)&Vsh[cur][(dg << 4) + rr][rg << 3];
          const half8 vfl2 = *(const half8*)&Vsl[cur][(dg << 4) + rr][rg << 3];
          oacc[qf][dg] = __builtin_amdgcn_mfma_f32_16x16x32_f16(pah, vfh2, oacc[qf][dg], 0, 0, 0);
          oacc[qf][dg] = __builtin_amdgcn_mfma_f32_16x16x32_f16(pah, vfl2, oacc[qf][dg], 0, 0, 0);
          oacc[qf][dg] = __builtin_amdgcn_mfma_f32_16x16x32_f16(pal, vfh2, oacc[qf][dg], 0, 0, 0);
        }
        __builtin_amdgcn_s_setprio(0);
      }
    }
    if (havenext) {
      *(half8*)&Vsh[cur ^ 1][vr][vs] = nvh;
      *(half8*)&Vsl[cur ^ 1][vr][vs] = nvl;
    }
    __syncthreads();
  }
#pragma unroll
  for (int qf = 0; qf < 2; ++qf) {
    float li[4];
#pragma unroll
    for (int r = 0; r < 4; ++r)
      li[r] = __shfl(lreg[qf], (lane & 48) | ((rg << 2) + r));
#pragma unroll
    for (int dg = 0; dg < 4; ++dg)
#pragma unroll
      for (int r = 0; r < 4; ++r) {
        const int qloc = (rg << 2) + r;
        const float ov = oacc[qf][dg][r] / (li[r] * SPC);
        const _Float16 hh2 = (_Float16)ov;
        const size_t off = (tokbase + q0w + (qf << 4) + qloc) * DIM + hcol + (dg << 4) + rr;
        Oh[off] = hh2;
        Ol[off] = (_Float16)(ov - (float)hh2);
      }
  }
}

extern "C" void kernel_launch(void* const* d_in, const int* in_sizes, int n_in,
                              void* d_out, int out_size, void* d_ws, size_t ws_size,
                              hipStream_t stream) {
  (void)in_sizes; (void)n_in; (void)out_size; (void)ws_size;
  const float* x    = (const float*)d_in[0];
  const float* n1w  = (const float*)d_in[1];
  const float* n2w  = (const float*)d_in[2];
  const float* wq   = (const float*)d_in[3];
  const float* wk   = (const float*)d_in[4];
  const float* wv   = (const float*)d_in[5];
  const float* wo   = (const float*)d_in[6];
  const float* qnw  = (const float*)d_in[7];
  const float* knw  = (const float*)d_in[8];
  const float* gw   = (const float*)d_in[9];
  const float* moesrc[12] = {
    (const float*)d_in[10], (const float*)d_in[11],
    (const float*)d_in[12], (const float*)d_in[13], (const float*)d_in[14],
    (const float*)d_in[15], (const float*)d_in[16], (const float*)d_in[17], (const float*)d_in[18],
    (const float*)d_in[19], (const float*)d_in[20], (const float*)d_in[21]
  };
  float* outp = (float*)d_out;

  char* p = (char*)d_ws;
  auto alloc = [&](size_t bytes) { void* r = (void*)p; p += (bytes + 255) & ~(size_t)255; return r; };
  const size_t NC = (size_t)NTOK * DIM;
  _Float16* hh = (_Float16*)alloc(NC * 2);
  _Float16* hl = (_Float16*)alloc(NC * 2);
  _Float16* qh = (_Float16*)alloc(NC * 2);   // qh..vtl reused as MoE arena
  _Float16* ql = (_Float16*)alloc(NC * 2);
  _Float16* kh = (_Float16*)alloc(NC * 2);
  _Float16* kl = (_Float16*)alloc(NC * 2);
  _Float16* vth = (_Float16*)alloc(NC * 2);
  _Float16* vtl = (_Float16*)alloc(NC * 2);
  unsigned short* xfb = (unsigned short*)alloc(NC * 2);
  float* wts = (float*)alloc((size_t)NTOK * 4 * 4);
  _Float16* awh = (_Float16*)alloc((size_t)4 * 1024 * 1024 * 2);
  _Float16* awl = (_Float16*)alloc((size_t)4 * 1024 * 1024 * 2);
  unsigned short* moeW = (unsigned short*)alloc((size_t)28311552 * 2);
  int* idxP = (int*)alloc((size_t)9216 * 4);
  int* meta = (int*)alloc(512);
  int* work = (int*)alloc((size_t)4 * 8 * MAXI * 4);
  unsigned short* e0t = (unsigned short*)qh;    // 16 MB (qh+ql)
  unsigned short* e1a = (unsigned short*)kh;    // 16 MB (kh+kl)
  unsigned short* e2a = (unsigned short*)vth;   // 16 MB (vth+vtl), reused as e2c
  unsigned short* e1b = (unsigned short*)alloc((size_t)NTOK * 2048 * 2);
  unsigned short* e2b = (unsigned short*)alloc((size_t)NTOK * 2048 * 2);
  unsigned short* e3a = (unsigned short*)alloc((size_t)NTOK * 1024 * 2);
  unsigned short* e3b = (unsigned short*)alloc((size_t)NTOK * 2048 * 2);
  unsigned short* e2c = e2a;

  const size_t moff[12] = {0, 2097152, 4194304, 6291456, 8388608, 10485760,
                           12582912, 16777216, 20971520, 23068672, 24117248, 26214400};
  auto mw = [&](int i) -> const unsigned short* { return moeW + moff[i]; };

  // ---- weight conversions ----
  cvt_attn4_k<<<dim3(1024, 4), dim3(256), 0, stream>>>(wq, wk, wv, wo, awh, awl);
  cvt_moe_all_k<<<dim3(4096, 12), dim3(256), 0, stream>>>(
      moesrc[0], moesrc[1], moesrc[2], moesrc[3], moesrc[4], moesrc[5],
      moesrc[6], moesrc[7], moesrc[8], moesrc[9], moesrc[10], moesrc[11], moeW);
  const _Float16* woh = awh + (3 << 20); const _Float16* wol = awl + (3 << 20);

  // ---- attention path (fp16x2) ----
  rms_split_k<<<dim3(NTOK), dim3(256), 0, stream>>>(x, n1w, hh, hl);
  gemm_split_k<3><<<dim3(24, 32), dim3(256), 0, stream>>>(
      hh, hl, awh, awl, 1024, 3072, qh, ql, 1.0f / SW, nullptr, nullptr,
      kh, kl, vth, vtl, qnw, knw);
  attn_k<<<dim3(512), dim3(256), 0, stream>>>(qh, ql, kh, kl, vth, vtl, hh, hl);
  gemm_split_k<1><<<dim3(8, 32), dim3(256), 0, stream>>>(
      hh, hl, woh, wol, 1024, 1024, nullptr, nullptr, 1.0f / (SA * SW), x, outp,
      nullptr, nullptr, nullptr, nullptr, nullptr, nullptr);

  // ---- MoE (sparse top-2, dense work-list phases, scatter into outp) ----
  rmsgate_k<<<dim3(NTOK), dim3(256), 0, stream>>>(outp, n2w, gw, xfb, wts);

  MoeCfg cfg;
  const int nbn_tab[4][4] = {{16, 16, 16, 8},
                             {8, 16, 16, 16},
                             {0, 8, 16, 0},
                             {0, 0, 8, 8}};
  const int ks_tab[4][4]  = {{1, 1, 1, 1},
                             {2, 1, 1, 1},
                             {1, 2, 1, 1},
                             {1, 1, 2, 2}};
  for (int pp = 0; pp < 4; ++pp)
    for (int ee = 0; ee < 4; ++ee) { cfg.nbn[pp][ee] = nbn_tab[pp][ee]; cfg.ks[pp][ee] = ks_tab[pp][ee]; }

  route2_k<<<dim3(1), dim3(256), 0, stream>>>(wts, idxP, meta, work, cfg);

  auto mk = [&](const unsigned short* A, const unsigned short* B, unsigned short* outb,
                const unsigned short* other, int K, int nbn, int act, int ep, int gath, int ks) {
    SubOpP s; s.A = A; s.Bw = B; s.outb = outb; s.other = other;
    s.K = K; s.nbn = nbn; s.act = act; s.ep = ep; s.gath = gath; s.ks = ks;
    return s;
  };
  const SubOpP none = mk(nullptr, nullptr, nullptr, nullptr, 1024, 0, 0, 0, 0, 1);

  PhaseP p1;
  p1.op[0] = mk(xfb, mw(0), e0t, nullptr, 1024, 16, 1, 0, 1, 1);  // e0: gelu(x@up)
  p1.op[1] = mk(xfb, mw(3), e1a, nullptr, 1024, 16, 0, 0, 1, 1);  // e1: x@w2 raw
  p1.op[2] = mk(xfb, mw(5), e2a, nullptr, 1024, 16, 1, 0, 1, 1);  // e2: gelu(x@l1)
  p1.op[3] = mk(xfb, mw(9), e3a, nullptr, 1024, 8, 1, 0, 1, 1);   // e3: gelu(x@dn)
  gemm_moe_k<<<dim3(8, MAXI), dim3(256), 0, stream>>>(p1, meta, idxP, wts, outp, work);

  PhaseP p2;
  p2.op[0] = mk(e0t, mw(1), nullptr, nullptr, 2048, 8, 0, 2, 0, 2);  // e0 down -> outp
  p2.op[1] = mk(xfb, mw(2), e1b, e1a, 1024, 16, 0, 1, 1, 1);         // e1: silu(x@w1)*e1a
  p2.op[2] = mk(e2a, mw(6), e2b, nullptr, 2048, 16, 1, 0, 0, 1);     // e2: gelu(@l2)
  p2.op[3] = mk(e3a, mw(10), e3b, nullptr, 1024, 16, 1, 0, 0, 1);    // e3: gelu(@up)
  gemm_moe_k<<<dim3(8, MAXI), dim3(256), 0, stream>>>(p2, meta, idxP, wts, outp, work + 8 * MAXI);

  PhaseP p3;
  p3.op[0] = none;
  p3.op[1] = mk(e1b, mw(4), nullptr, nullptr, 2048, 8, 0, 2, 0, 2);  // e1 down -> outp
  p3.op[2] = mk(e2b, mw(7), e2c, nullptr, 2048, 16, 1, 0, 0, 1);     // e2: gelu(@l3)
  p3.op[3] = none;
  gemm_moe_k<<<dim3(8, MAXI), dim3(256), 0, stream>>>(p3, meta, idxP, wts, outp, work + 16 * MAXI);

  PhaseP p4;
  p4.op[0] = none;
  p4.op[1] = none;
  p4.op[2] = mk(e2c, mw(8), nullptr, nullptr, 2048, 8, 0, 2, 0, 2);  // e2 l4 -> outp
  p4.op[3] = mk(e3b, mw(11), nullptr, nullptr, 2048, 8, 0, 2, 0, 2); // e3 out -> outp
  gemm_moe_k<<<dim3(8, MAXI), dim3(256), 0, stream>>>(p4, meta, idxP, wts, outp, work + 24 * MAXI);
}

// Round 14
// 573.707 us; speedup vs baseline: 1.2227x; 1.0418x over previous
//
#include <hip/hip_runtime.h>
#include <math.h>

#define DIM   1024
#define NTOK  4096
#define TSEQ  1024
#define NHEAD 16
#define MPROT 256
#define EPSR  1.1920929e-07f
#define SA    64.0f
#define SW    256.0f
#define SPC   64.0f
#define MAXI  320

typedef __attribute__((ext_vector_type(8))) short          short8;
typedef __attribute__((ext_vector_type(8))) _Float16       half8;
typedef __attribute__((ext_vector_type(4))) _Float16       half4;
typedef __attribute__((ext_vector_type(4))) float          f32x4;
typedef __attribute__((ext_vector_type(4))) unsigned short us4;

static __device__ __forceinline__ float bf2f(unsigned short s) {
  union { unsigned int u; float f; } c; c.u = ((unsigned int)s) << 16; return c.f;
}
static __device__ __forceinline__ unsigned short f2bf(float f) {
  union { float f; unsigned int u; } c; c.f = f;
  return (unsigned short)((c.u + 0x7fffu + ((c.u >> 16) & 1u)) >> 16);
}
static __device__ __forceinline__ void gload16(void* lds, const void* g) {
  __builtin_amdgcn_global_load_lds(
      (__attribute__((address_space(1))) void*)const_cast<void*>(g),
      (__attribute__((address_space(3))) void*)lds, 16, 0, 0);
}

// XCD swizzle for dense split-GEMMs: stripe m-blocks across XCDs.
static __device__ __forceinline__ void tile_swz(int& m0, int& n0) {
  const int gx = gridDim.x;
  const int L = blockIdx.y * gx + blockIdx.x;
  const int xcd = L & 7;
  const int j = L >> 3;
  const int mbq = j / gx;
  const int nb = j - mbq * gx;
  m0 = ((mbq << 3) | xcd) << 7;
  n0 = nb << 7;
}

// ---------------- conversions ----------------
__global__ __launch_bounds__(256) void cvt_attn4_k(const float* __restrict__ wq,
                                                   const float* __restrict__ wk,
                                                   const float* __restrict__ wv,
                                                   const float* __restrict__ wo,
                                                   _Float16* __restrict__ dh,
                                                   _Float16* __restrict__ dl) {
  const int wi = blockIdx.y;
  const float* s = (wi == 0) ? wq : (wi == 1) ? wk : (wi == 2) ? wv : wo;
  const int i = blockIdx.x * 256 + threadIdx.x;
  const size_t off4 = ((size_t)wi << 20) >> 2;
  const float4 v = ((const float4*)s)[i];
  float a0 = v.x * SW, a1 = v.y * SW, a2 = v.z * SW, a3 = v.w * SW;
  half4 hv, lv;
  _Float16 h0 = (_Float16)a0; hv[0] = h0; lv[0] = (_Float16)(a0 - (float)h0);
  _Float16 h1 = (_Float16)a1; hv[1] = h1; lv[1] = (_Float16)(a1 - (float)h1);
  _Float16 h2 = (_Float16)a2; hv[2] = h2; lv[2] = (_Float16)(a2 - (float)h2);
  _Float16 h3 = (_Float16)a3; hv[3] = h3; lv[3] = (_Float16)(a3 - (float)h3);
  ((half4*)dh)[off4 + i] = hv; ((half4*)dl)[off4 + i] = lv;
}

__global__ __launch_bounds__(256) void cvt_moe_all_k(
    const float* s0, const float* s1, const float* s2, const float* s3,
    const float* s4, const float* s5, const float* s6, const float* s7,
    const float* s8, const float* s9, const float* s10, const float* s11,
    unsigned short* __restrict__ dst) {
  const int n4tab[12] = {524288, 524288, 524288, 524288, 524288, 524288,
                         1048576, 1048576, 524288, 262144, 524288, 524288};
  const size_t offtab[12] = {0, 2097152, 4194304, 6291456, 8388608, 10485760,
                             12582912, 16777216, 20971520, 23068672, 24117248, 26214400};
  const int wi = blockIdx.y;
  const int i = blockIdx.x * 256 + threadIdx.x;
  if (i >= n4tab[wi]) return;
  const float* s;
  switch (wi) {
    case 0: s = s0; break; case 1: s = s1; break; case 2: s = s2; break;
    case 3: s = s3; break; case 4: s = s4; break; case 5: s = s5; break;
    case 6: s = s6; break; case 7: s = s7; break; case 8: s = s8; break;
    case 9: s = s9; break; case 10: s = s10; break; default: s = s11; break;
  }
  const float4 v = ((const float4*)s)[i];
  us4 o; o[0] = f2bf(v.x); o[1] = f2bf(v.y); o[2] = f2bf(v.z); o[3] = f2bf(v.w);
  ((us4*)(dst + offtab[wi]))[i] = o;
}

// ---------------- RMS norms ----------------
__global__ __launch_bounds__(256) void rms_split_k(const float* __restrict__ in,
                                                   const float* __restrict__ wgt,
                                                   _Float16* __restrict__ oh,
                                                   _Float16* __restrict__ ol) {
  const int row = blockIdx.x, tid = threadIdx.x;
  const float4 v = ((const float4*)(in + (size_t)row * DIM))[tid];
  float ss = v.x * v.x + v.y * v.y + v.z * v.z + v.w * v.w;
#pragma unroll
  for (int o = 32; o; o >>= 1) ss += __shfl_xor(ss, o);
  __shared__ float red[4];
  if ((tid & 63) == 0) red[tid >> 6] = ss;
  __syncthreads();
  const float sc = rsqrtf((red[0] + red[1] + red[2] + red[3]) * (1.0f / DIM) + EPSR) * SA;
  const float4 wv = ((const float4*)wgt)[tid];
  float a[4] = {v.x * sc * wv.x, v.y * sc * wv.y, v.z * sc * wv.z, v.w * sc * wv.w};
  half4 hv, lv;
#pragma unroll
  for (int j = 0; j < 4; ++j) {
    _Float16 hh = (_Float16)a[j]; hv[j] = hh; lv[j] = (_Float16)(a[j] - (float)hh);
  }
  ((half4*)(oh + (size_t)row * DIM))[tid] = hv;
  ((half4*)(ol + (size_t)row * DIM))[tid] = lv;
}

// fused RMSNorm(bf16 out) + gate logits/softmax/top-2
__global__ __launch_bounds__(256) void rmsgate_k(const float* __restrict__ x2,
                                                 const float* __restrict__ n2w,
                                                 const float* __restrict__ gw,
                                                 unsigned short* __restrict__ xfb,
                                                 float* __restrict__ wts) {
  const int row = blockIdx.x, tid = threadIdx.x;
  const float4 v = ((const float4*)(x2 + (size_t)row * DIM))[tid];
  float ss = v.x * v.x + v.y * v.y + v.z * v.z + v.w * v.w;
#pragma unroll
  for (int o = 32; o; o >>= 1) ss += __shfl_xor(ss, o);
  __shared__ float red[4];
  __shared__ float redE[4][4];
  const int w = tid >> 6, lane = tid & 63;
  if (lane == 0) red[w] = ss;
  __syncthreads();
  const float sc = rsqrtf((red[0] + red[1] + red[2] + red[3]) * (1.0f / DIM) + EPSR);
  const float4 nw = ((const float4*)n2w)[tid];
  const float xn0 = v.x * sc * nw.x, xn1 = v.y * sc * nw.y;
  const float xn2 = v.z * sc * nw.z, xn3 = v.w * sc * nw.w;
  us4 ob; ob[0] = f2bf(xn0); ob[1] = f2bf(xn1); ob[2] = f2bf(xn2); ob[3] = f2bf(xn3);
  ((us4*)(xfb + (size_t)row * DIM))[tid] = ob;
#pragma unroll
  for (int e = 0; e < 4; ++e) {
    const float4 g = ((const float4*)(gw + (size_t)e * DIM))[tid];
    float d = xn0 * g.x + xn1 * g.y + xn2 * g.z + xn3 * g.w;
#pragma unroll
    for (int o = 32; o; o >>= 1) d += __shfl_xor(d, o);
    if (lane == 0) redE[w][e] = d;
  }
  __syncthreads();
  if (tid == 0) {
    float lg[4];
#pragma unroll
    for (int e = 0; e < 4; ++e) lg[e] = redE[0][e] + redE[1][e] + redE[2][e] + redE[3][e];
    const float mx = fmaxf(fmaxf(lg[0], lg[1]), fmaxf(lg[2], lg[3]));
    float pe[4]; float sum = 0.0f;
#pragma unroll
    for (int e = 0; e < 4; ++e) { pe[e] = __expf(lg[e] - mx); sum += pe[e]; }
#pragma unroll
    for (int e = 0; e < 4; ++e) pe[e] /= sum;
    int i1 = 0;
    for (int e = 1; e < 4; ++e) if (pe[e] > pe[i1]) i1 = e;
    int i2 = -1;
    for (int e = 0; e < 4; ++e) { if (e == i1) continue; if (i2 < 0 || pe[e] > pe[i2]) i2 = e; }
    const float s2 = pe[i1] + pe[i2] + 1e-8f;
    float o[4] = {0.f, 0.f, 0.f, 0.f};
    o[i1] = pe[i1] / s2; o[i2] = pe[i2] / s2;
    float4 r; r.x = o[0]; r.y = o[1]; r.z = o[2]; r.w = o[3];
    *(float4*)(wts + (size_t)row * 4) = r;
  }
}

// ---------------- routing + dense per-XCD work lists ----------------
struct MoeCfg { int nbn[4][4]; int ks[4][4]; };

__global__ __launch_bounds__(256) void route2_k(const float* __restrict__ wts,
                                                int* __restrict__ idxP,
                                                int* __restrict__ meta,
                                                int* __restrict__ work,
                                                MoeCfg cfg) {
  const int tid = threadIdx.x, w = tid >> 6, lane = tid & 63;
  __shared__ int wsum[4];
  __shared__ int baseS;
  int off = 0;
  for (int e = 0; e < 4; ++e) {
    if (tid == 0) baseS = 0;
    __syncthreads();
    for (int c = 0; c < 16; ++c) {
      const int tok = (c << 8) + tid;
      const bool pred = wts[(size_t)tok * 4 + e] > 0.0f;
      const unsigned long long m = __ballot(pred);
      const int lanepre = __popcll(m & ((1ull << lane) - 1ull));
      if (lane == 0) wsum[w] = __popcll(m);
      __syncthreads();
      int wpre = 0;
#pragma unroll
      for (int i = 0; i < 4; ++i) wpre += (i < w) ? wsum[i] : 0;
      const int tot = wsum[0] + wsum[1] + wsum[2] + wsum[3];
      if (pred) idxP[off + baseS + wpre + lanepre] = tok;
      __syncthreads();
      if (tid == 0) baseS += tot;
      __syncthreads();
    }
    const int cnt = baseS;
    const int padded = (cnt + 127) & ~127;
    for (int j = cnt + tid; j < padded; j += 256) idxP[off + j] = -1;
    if (tid == 0) meta[80 + e] = off;
    const int mb0 = off >> 7, nmb = padded >> 7;
    for (int j = tid; j < nmb; j += 256) meta[mb0 + j] = e;
    off += padded;
    __syncthreads();
  }
  for (int j = (off >> 7) + tid; j < 72; j += 256) meta[j] = -1;
  for (int j = tid; j < 4 * 8 * MAXI; j += 256) work[j] = -1;
  __syncthreads();
  if (tid < 32) {
    const int p = tid >> 3, x = tid & 7;
    int* wb = work + p * (8 * MAXI);
    int n = 0;
    const int totmb = off >> 7;
    for (int mb = x; mb < totmb; mb += 8) {
      const int e = meta[mb];
      const int nbn = cfg.nbn[p][e];
      const int ks = cfg.ks[p][e];
      for (int nb = 0; nb < nbn; ++nb)
        for (int k = 0; k < ks; ++k) {
          wb[n * 8 + x] = mb | (nb << 8) | (k << 16);
          ++n;
        }
    }
  }
}

// ---------------- packed grouped sparse bf16 GEMM ----------------
// 128x64 tiles, single-buffer 24 KB LDS, 6 blocks/CU: maximize TLP for the
// latency-bound sparse-MoE regime (nbn counts 64-wide n-blocks; n0 = nb<<6).
struct SubOpP {
  const unsigned short* A;
  const unsigned short* Bw;
  unsigned short* outb;
  const unsigned short* other;
  int K, nbn, act, ep, gath, ks;  // ep: 0 store, 1 silu*other, 2 scatter atomicAdd->outp (masked)
};
struct PhaseP { SubOpP op[4]; };  // indexed by expert

__global__ __launch_bounds__(256, 6) void gemm_moe_k(PhaseP ph,
                                                     const int* __restrict__ meta,
                                                     const int* __restrict__ idxP,
                                                     const float* __restrict__ wts,
                                                     float* __restrict__ outp,
                                                     const int* __restrict__ wk) {
  __shared__ unsigned short As[128][64];
  __shared__ unsigned short Bs[64][64];
  const int item = wk[blockIdx.y * 8 + blockIdx.x];
  if (item < 0) return;
  const int mb = item & 255;
  const int nb = (item >> 8) & 255;
  const int kpart = (item >> 16) & 3;
  const int e = meta[mb];
  SubOpP op;
  switch (e) {
    case 0: op = ph.op[0]; break;
    case 1: op = ph.op[1]; break;
    case 2: op = ph.op[2]; break;
    default: op = ph.op[3]; break;
  }
  const int m0p = mb << 7;
  const int lr0 = m0p - meta[80 + e];
  const int n0 = nb << 6;
  const int F = op.nbn << 6;
  const int K = op.K;
  const int tid = threadIdx.x;
  const int w = tid >> 6, lane = tid & 63;
  const int wr = ((w >> 1) << 6), wc = ((w & 1) << 5);
  const int rr = lane & 15, kgl = lane >> 4;
  const int srow = tid >> 3, sslot = tid & 7;

  int grow[4];
#pragma unroll
  for (int i = 0; i < 4; ++i) {
    const int r = (i << 5) + srow;
    if (op.gath) {
      const int t = idxP[m0p + r];
      grow[i] = (t < 0) ? 0 : t;
    } else {
      grow[i] = lr0 + r;
    }
  }

  f32x4 acc[4][2];
#pragma unroll
  for (int a_ = 0; a_ < 4; ++a_)
#pragma unroll
    for (int b_ = 0; b_ < 2; ++b_) acc[a_][b_] = (f32x4){0.f, 0.f, 0.f, 0.f};

  int kt0 = 0, ktN = K >> 6;
  if (op.ks > 1) { const int seg = ktN / op.ks; kt0 = kpart * seg; ktN = kt0 + seg; }
  for (int kt = kt0; kt < ktN; ++kt) {
    const int k0 = kt << 6;
#pragma unroll
    for (int i = 0; i < 4; ++i) {
      const int r = (i << 5) + srow;
      const int ls = sslot ^ (r & 7);
      gload16(&As[(i << 5) + (w << 3)][0], op.A + (size_t)grow[i] * K + k0 + (ls << 3));
    }
#pragma unroll
    for (int i = 0; i < 2; ++i) {
      const int r = (i << 5) + srow;
      const int ls = sslot ^ (r & 7);
      gload16(&Bs[(i << 5) + (w << 3)][0], op.Bw + (size_t)(n0 + r) * K + k0 + (ls << 3));
    }
    __syncthreads();
    short8 af[4][2], bfr[2][2];
#pragma unroll
    for (int ks = 0; ks < 2; ++ks) {
#pragma unroll
      for (int f = 0; f < 4; ++f) {
        const int row = wr + (f << 4) + rr;
        const int kg = (ks << 2) + kgl;
        af[f][ks] = *(const short8*)&As[row][(kg ^ (row & 7)) << 3];
      }
#pragma unroll
      for (int f = 0; f < 2; ++f) {
        const int col = wc + (f << 4) + rr;
        const int kg = (ks << 2) + kgl;
        bfr[f][ks] = *(const short8*)&Bs[col][(kg ^ (col & 7)) << 3];
      }
    }
#pragma unroll
    for (int fi = 0; fi < 4; ++fi)
#pragma unroll
      for (int fj = 0; fj < 2; ++fj)
#pragma unroll
        for (int ks = 0; ks < 2; ++ks)
          acc[fi][fj] = __builtin_amdgcn_mfma_f32_16x16x32_bf16(
              af[fi][ks], bfr[fj][ks], acc[fi][fj], 0, 0, 0);
    __syncthreads();
  }
#pragma unroll
  for (int fi = 0; fi < 4; ++fi)
#pragma unroll
    for (int fj = 0; fj < 2; ++fj) {
      const int col = n0 + wc + (fj << 4) + rr;
#pragma unroll
      for (int r = 0; r < 4; ++r) {
        const int rl = wr + (fi << 4) + (kgl << 2) + r;
        float v = acc[fi][fj][r];
        if (op.act) v = 0.5f * v * (1.0f + erff(v * 0.70710678118654752f));
        if (op.ep == 0) {
          op.outb[(size_t)(lr0 + rl) * F + col] = f2bf(v);
        } else if (op.ep == 1) {
          const size_t off = (size_t)(lr0 + rl) * F + col;
          const float sv = v / (1.0f + __expf(-v));
          op.outb[off] = f2bf(sv * bf2f(op.other[off]));
        } else {
          const int tok = idxP[m0p + rl];
          if (tok >= 0 && col >= MPROT)
            atomicAdd(&outp[(size_t)tok * DIM + col], wts[(size_t)tok * 4 + e] * v);
        }
      }
    }
}

// ---------------- fp16x2 split GEMM (3-term), single-buffer LDS ----------------
// EP: 1 = fp32: resid + masked(v); 3 = fused QKV epilogue with fused qk-norm
template <int EP>
__global__ __launch_bounds__(256, 4) void gemm_split_k(
    const _Float16* __restrict__ Ah, const _Float16* __restrict__ Al,
    const _Float16* __restrict__ Bh, const _Float16* __restrict__ Bl,
    int K, int F,
    _Float16* __restrict__ Oh, _Float16* __restrict__ Ol, float oscale,
    const float* __restrict__ resid, float* __restrict__ outf,
    _Float16* __restrict__ K2h, _Float16* __restrict__ K2l,
    _Float16* __restrict__ V2h, _Float16* __restrict__ V2l,
    const float* __restrict__ qnw, const float* __restrict__ knw) {
  __shared__ _Float16 AsH[128][32], AsL[128][32];
  __shared__ _Float16 BsH[128][32], BsL[128][32];
  const int tid = threadIdx.x;
  const int w = tid >> 6, lane = tid & 63;
  const int wr = ((w >> 1) << 6), wc = ((w & 1) << 6);
  int m0, n0;
  tile_swz(m0, n0);
  const int rr = lane & 15, kgl = lane >> 4;
  const int srow = tid >> 2, sslot = tid & 3;

  f32x4 acc[4][4];
#pragma unroll
  for (int a_ = 0; a_ < 4; ++a_)
#pragma unroll
    for (int b_ = 0; b_ < 4; ++b_) acc[a_][b_] = (f32x4){0.f, 0.f, 0.f, 0.f};

  const int KT = K >> 5;
  for (int kt = 0; kt < KT; ++kt) {
    const int k0 = kt << 5;
#pragma unroll
    for (int i = 0; i < 2; ++i) {
      const int r = (i << 6) + srow;
      const int ls = sslot ^ ((r >> 1) & 3);
      const size_t ga = (size_t)(m0 + r) * K + k0 + (ls << 3);
      const size_t gb = (size_t)(n0 + r) * K + k0 + (ls << 3);
      const int lr = (i << 6) + (w << 4);
      gload16(&AsH[lr][0], Ah + ga);
      gload16(&AsL[lr][0], Al + ga);
      gload16(&BsH[lr][0], Bh + gb);
      gload16(&BsL[lr][0], Bl + gb);
    }
    __syncthreads();
    half8 ah[4], al[4], bh[4], bl[4];
#pragma unroll
    for (int f = 0; f < 4; ++f) {
      const int row = wr + (f << 4) + rr;
      const int pa = (kgl ^ ((row >> 1) & 3)) << 3;
      ah[f] = *(const half8*)&AsH[row][pa];
      al[f] = *(const half8*)&AsL[row][pa];
      const int col = wc + (f << 4) + rr;
      const int pb = (kgl ^ ((col >> 1) & 3)) << 3;
      bh[f] = *(const half8*)&BsH[col][pb];
      bl[f] = *(const half8*)&BsL[col][pb];
    }
#pragma unroll
    for (int fi = 0; fi < 4; ++fi)
#pragma unroll
      for (int fj = 0; fj < 4; ++fj) {
        acc[fi][fj] = __builtin_amdgcn_mfma_f32_16x16x32_f16(ah[fi], bh[fj], acc[fi][fj], 0, 0, 0);
        acc[fi][fj] = __builtin_amdgcn_mfma_f32_16x16x32_f16(ah[fi], bl[fj], acc[fi][fj], 0, 0, 0);
        acc[fi][fj] = __builtin_amdgcn_mfma_f32_16x16x32_f16(al[fi], bh[fj], acc[fi][fj], 0, 0, 0);
      }
    __syncthreads();
  }

  if (EP == 3 && n0 < 2048) {
    // q (n0<1024) or k tile: fuse per-(row,head) RMS norm over the 64 head dims.
    const bool isq = (n0 < 1024);
    _Float16* ph = isq ? Oh : K2h;
    _Float16* pl = isq ? Ol : K2l;
    const float* wvec = isq ? qnw : knw;
    float wreg[4];
#pragma unroll
    for (int fj = 0; fj < 4; ++fj) wreg[fj] = wvec[(fj << 4) + rr];
#pragma unroll
    for (int fi = 0; fi < 4; ++fi) {
#pragma unroll
      for (int r = 0; r < 4; ++r) {
        float vv[4]; float ss = 0.f;
#pragma unroll
        for (int fj = 0; fj < 4; ++fj) {
          vv[fj] = acc[fi][fj][r] * oscale;
          ss += vv[fj] * vv[fj];
        }
        ss += __shfl_xor(ss, 1);
        ss += __shfl_xor(ss, 2);
        ss += __shfl_xor(ss, 4);
        ss += __shfl_xor(ss, 8);
        const float sc = rsqrtf(ss * (1.0f / (64.0f * SA * SA)) + EPSR);
        const int row = m0 + wr + (fi << 4) + (kgl << 2) + r;
#pragma unroll
        for (int fj = 0; fj < 4; ++fj) {
          const int c = (n0 + wc + (fj << 4) + rr) & 1023;
          const float nv = vv[fj] * sc * wreg[fj];
          const _Float16 hh2 = (_Float16)nv;
          const size_t off = (size_t)row * DIM + c;
          ph[off] = hh2; pl[off] = (_Float16)(nv - (float)hh2);
        }
      }
    }
    return;
  }

#pragma unroll
  for (int fi = 0; fi < 4; ++fi)
#pragma unroll
    for (int fj = 0; fj < 4; ++fj) {
      const int col = n0 + wc + (fj << 4) + rr;
      const int rowb = m0 + wr + (fi << 4) + (kgl << 2);
      if (EP == 3) {
        const int c2 = col - 2048;
        half4 h4, l4;
#pragma unroll
        for (int r = 0; r < 4; ++r) {
          const float v = acc[fi][fj][r] * oscale;
          const _Float16 hh2 = (_Float16)v;
          h4[r] = hh2; l4[r] = (_Float16)(v - (float)hh2);
        }
        const size_t vt = ((size_t)((rowb >> 10) << 4) + (size_t)(c2 >> 6)) * 65536 +
                          (size_t)(c2 & 63) * 1024 + (size_t)(rowb & 1023);
        *(half4*)&V2h[vt] = h4;
        *(half4*)&V2l[vt] = l4;
      } else {
#pragma unroll
        for (int r = 0; r < 4; ++r) {
          const size_t off = (size_t)(rowb + r) * F + col;
          const float v = acc[fi][fj][r] * oscale;
          outf[off] = resid[off] + (col >= MPROT ? v : 0.0f);
        }
      }
    }
}

// ---------------- flash attention, causal, fp16x2 split, swapped-QK ----------------
// load-balanced qt pairing: blocks 2j/2j+1 get qt = pt / 7-pt (uniform 36 tiles per pair)
__global__ __launch_bounds__(256, 2) void attn_k(
    const _Float16* __restrict__ Qh, const _Float16* __restrict__ Ql,
    const _Float16* __restrict__ Kh, const _Float16* __restrict__ Kl,
    const _Float16* __restrict__ Vth, const _Float16* __restrict__ Vtl,
    _Float16* __restrict__ Oh, _Float16* __restrict__ Ol) {
  __shared__ _Float16 Ksh[2][32][64], Ksl[2][32][64];
  __shared__ _Float16 Vsh[2][64][40], Vsl[2][64][40];
  __shared__ _Float16 Plh[4][16][40], Pll[4][16][40];
  const int n = blockIdx.x;
  const int j = n >> 1, s = n & 1;
  const int pt = j >> 6;
  const int qt = s ? (7 - pt) : pt;
  const int bh = j & 63;
  const int b = bh >> 4, h = bh & 15;
  const int tid = threadIdx.x, w = tid >> 6, lane = tid & 63;
  const int rr = lane & 15, rg = lane >> 4;
  const size_t tokbase = (size_t)b * TSEQ;
  const int hcol = h << 6;
  const size_t vtbase = (size_t)bh << 16;
  const int q0w = (qt << 7) + (w << 5);
  const float sscale = 0.125f / (SA * SA);

  half8 qfh[2][2], qfl[2][2];
#pragma unroll
  for (int qf = 0; qf < 2; ++qf)
#pragma unroll
    for (int ks = 0; ks < 2; ++ks) {
      const size_t off = (tokbase + q0w + (qf << 4) + rr) * DIM + hcol + (ks << 5) + (rg << 3);
      qfh[qf][ks] = *(const half8*)&Qh[off];
      qfl[qf][ks] = *(const half8*)&Ql[off];
    }

  f32x4 oacc[2][4];
#pragma unroll
  for (int qf = 0; qf < 2; ++qf)
#pragma unroll
    for (int dg = 0; dg < 4; ++dg) oacc[qf][dg] = (f32x4){0.f, 0.f, 0.f, 0.f};
  float mreg[2] = {-INFINITY, -INFINITY}, lreg[2] = {0.f, 0.f};

  const int kr = (w << 3) + (lane >> 3);
  const int kswz = ((lane & 7) ^ (kr & 7)) << 3;
  const int vr = tid >> 2;
  const int vs = (tid & 3) << 3;

  const int ntiles = (qt + 1) << 2;

  {
    gload16(&Ksh[0][w << 3][0], &Kh[(tokbase + kr) * DIM + hcol + kswz]);
    gload16(&Ksl[0][w << 3][0], &Kl[(tokbase + kr) * DIM + hcol + kswz]);
    const half8 vvh = *(const half8*)&Vth[vtbase + (size_t)vr * TSEQ + vs];
    const half8 vvl = *(const half8*)&Vtl[vtbase + (size_t)vr * TSEQ + vs];
    *(half8*)&Vsh[0][vr][vs] = vvh;
    *(half8*)&Vsl[0][vr][vs] = vvl;
    __syncthreads();
  }

  for (int t = 0; t < ntiles; ++t) {
    const int cur = t & 1;
    const int kv0 = t << 5;
    const bool havenext = (t + 1 < ntiles);
    half8 nvh, nvl;
    if (havenext) {
      const int kn = kv0 + 32;
      gload16(&Ksh[cur ^ 1][w << 3][0], &Kh[(tokbase + kn + kr) * DIM + hcol + kswz]);
      gload16(&Ksl[cur ^ 1][w << 3][0], &Kl[(tokbase + kn + kr) * DIM + hcol + kswz]);
      nvh = *(const half8*)&Vth[vtbase + (size_t)vr * TSEQ + kn + vs];
      nvl = *(const half8*)&Vtl[vtbase + (size_t)vr * TSEQ + kn + vs];
    }
    if (kv0 <= q0w + 31) {
      half8 kfh[2][2], kfl[2][2];
#pragma unroll
      for (int kt = 0; kt < 2; ++kt)
#pragma unroll
        for (int ks = 0; ks < 2; ++ks) {
          const int row = (kt << 4) + rr;
          const int sw = ((((ks << 2) + rg)) ^ (row & 7)) << 3;
          kfh[kt][ks] = *(const half8*)&Ksh[cur][row][sw];
          kfl[kt][ks] = *(const half8*)&Ksl[cur][row][sw];
        }
#pragma unroll
      for (int qf = 0; qf < 2; ++qf) {
        if (kv0 > q0w + (qf << 4) + 15) continue;
        f32x4 st[2];
        st[0] = (f32x4){0.f, 0.f, 0.f, 0.f};
        st[1] = (f32x4){0.f, 0.f, 0.f, 0.f};
        __builtin_amdgcn_s_setprio(1);
#pragma unroll
        for (int kt = 0; kt < 2; ++kt)
#pragma unroll
          for (int ks = 0; ks < 2; ++ks) {
            st[kt] = __builtin_amdgcn_mfma_f32_16x16x32_f16(kfh[kt][ks], qfh[qf][ks], st[kt], 0, 0, 0);
            st[kt] = __builtin_amdgcn_mfma_f32_16x16x32_f16(kfh[kt][ks], qfl[qf][ks], st[kt], 0, 0, 0);
            st[kt] = __builtin_amdgcn_mfma_f32_16x16x32_f16(kfl[kt][ks], qfh[qf][ks], st[kt], 0, 0, 0);
          }
        __builtin_amdgcn_s_setprio(0);
        const int qg = q0w + (qf << 4) + rr;
        float s2[2][4]; float mx = -INFINITY;
#pragma unroll
        for (int kt = 0; kt < 2; ++kt)
#pragma unroll
          for (int r = 0; r < 4; ++r) {
            float sv = st[kt][r] * sscale;
            if (kv0 + (kt << 4) + (rg << 2) + r > qg) sv = -INFINITY;
            s2[kt][r] = sv; mx = fmaxf(mx, sv);
          }
        mx = fmaxf(mx, __shfl_xor(mx, 16));
        mx = fmaxf(mx, __shfl_xor(mx, 32));
        const float mn = fmaxf(mreg[qf], mx);
        const float al = __expf(mreg[qf] - mn);
        mreg[qf] = mn;
        float p[2][4]; float rs = 0.f;
#pragma unroll
        for (int kt = 0; kt < 2; ++kt)
#pragma unroll
          for (int r = 0; r < 4; ++r) { p[kt][r] = __expf(s2[kt][r] - mn); rs += p[kt][r]; }
        rs += __shfl_xor(rs, 16);
        rs += __shfl_xor(rs, 32);
        lreg[qf] = lreg[qf] * al + rs;
#pragma unroll
        for (int kt = 0; kt < 2; ++kt) {
          half4 h4, l4;
#pragma unroll
          for (int r = 0; r < 4; ++r) {
            const float pv = p[kt][r] * SPC;
            const _Float16 ph = (_Float16)pv;
            h4[r] = ph; l4[r] = (_Float16)(pv - (float)ph);
          }
          *(half4*)&Plh[w][rr][(kt << 4) + (rg << 2)] = h4;
          *(half4*)&Pll[w][rr][(kt << 4) + (rg << 2)] = l4;
        }
        float alr[4];
#pragma unroll
        for (int r = 0; r < 4; ++r) alr[r] = __shfl(al, (lane & 48) | ((rg << 2) + r));
#pragma unroll
        for (int dg = 0; dg < 4; ++dg)
#pragma unroll
          for (int r = 0; r < 4; ++r) oacc[qf][dg][r] *= alr[r];
        const half8 pah = *(const half8*)&Plh[w][rr][rg << 3];
        const half8 pal = *(const half8*)&Pll[w][rr][rg << 3];
        __builtin_amdgcn_s_setprio(1);
#pragma unroll
        for (int dg = 0; dg < 4; ++dg) {
          const half8 vfh2 = *(const half8*)&Vsh[cur][(dg << 4) + rr][rg << 3];
          const half8 vfl2 = *(const half8*)&Vsl[cur][(dg << 4) + rr][rg << 3];
          oacc[qf][dg] = __builtin_amdgcn_mfma_f32_16x16x32_f16(pah, vfh2, oacc[qf][dg], 0, 0, 0);
          oacc[qf][dg] = __builtin_amdgcn_mfma_f32_16x16x32_f16(pah, vfl2, oacc[qf][dg], 0, 0, 0);
          oacc[qf][dg] = __builtin_amdgcn_mfma_f32_16x16x32_f16(pal, vfh2, oacc[qf][dg], 0, 0, 0);
        }
        __builtin_amdgcn_s_setprio(0);
      }
    }
    if (havenext) {
      *(half8*)&Vsh[cur ^ 1][vr][vs] = nvh;
      *(half8*)&Vsl[cur ^ 1][vr][vs] = nvl;
    }
    __syncthreads();
  }
#pragma unroll
  for (int qf = 0; qf < 2; ++qf) {
    float li[4];
#pragma unroll
    for (int r = 0; r < 4; ++r)
      li[r] = __shfl(lreg[qf], (lane & 48) | ((rg << 2) + r));
#pragma unroll
    for (int dg = 0; dg < 4; ++dg)
#pragma unroll
      for (int r = 0; r < 4; ++r) {
        const int qloc = (rg << 2) + r;
        const float ov = oacc[qf][dg][r] / (li[r] * SPC);
        const _Float16 hh2 = (_Float16)ov;
        const size_t off = (tokbase + q0w + (qf << 4) + qloc) * DIM + hcol + (dg << 4) + rr;
        Oh[off] = hh2;
        Ol[off] = (_Float16)(ov - (float)hh2);
      }
  }
}

extern "C" void kernel_launch(void* const* d_in, const int* in_sizes, int n_in,
                              void* d_out, int out_size, void* d_ws, size_t ws_size,
                              hipStream_t stream) {
  (void)in_sizes; (void)n_in; (void)out_size; (void)ws_size;
  const float* x    = (const float*)d_in[0];
  const float* n1w  = (const float*)d_in[1];
  const float* n2w  = (const float*)d_in[2];
  const float* wq   = (const float*)d_in[3];
  const float* wk   = (const float*)d_in[4];
  const float* wv   = (const float*)d_in[5];
  const float* wo   = (const float*)d_in[6];
  const float* qnw  = (const float*)d_in[7];
  const float* knw  = (const float*)d_in[8];
  const float* gw   = (const float*)d_in[9];
  const float* moesrc[12] = {
    (const float*)d_in[10], (const float*)d_in[11],
    (const float*)d_in[12], (const float*)d_in[13], (const float*)d_in[14],
    (const float*)d_in[15], (const float*)d_in[16], (const float*)d_in[17], (const float*)d_in[18],
    (const float*)d_in[19], (const float*)d_in[20], (const float*)d_in[21]
  };
  float* outp = (float*)d_out;

  char* p = (char*)d_ws;
  auto alloc = [&](size_t bytes) { void* r = (void*)p; p += (bytes + 255) & ~(size_t)255; return r; };
  const size_t NC = (size_t)NTOK * DIM;
  _Float16* hh = (_Float16*)alloc(NC * 2);
  _Float16* hl = (_Float16*)alloc(NC * 2);
  _Float16* qh = (_Float16*)alloc(NC * 2);   // qh..vtl reused as MoE arena
  _Float16* ql = (_Float16*)alloc(NC * 2);
  _Float16* kh = (_Float16*)alloc(NC * 2);
  _Float16* kl = (_Float16*)alloc(NC * 2);
  _Float16* vth = (_Float16*)alloc(NC * 2);
  _Float16* vtl = (_Float16*)alloc(NC * 2);
  unsigned short* xfb = (unsigned short*)alloc(NC * 2);
  float* wts = (float*)alloc((size_t)NTOK * 4 * 4);
  _Float16* awh = (_Float16*)alloc((size_t)4 * 1024 * 1024 * 2);
  _Float16* awl = (_Float16*)alloc((size_t)4 * 1024 * 1024 * 2);
  unsigned short* moeW = (unsigned short*)alloc((size_t)28311552 * 2);
  int* idxP = (int*)alloc((size_t)9216 * 4);
  int* meta = (int*)alloc(512);
  int* work = (int*)alloc((size_t)4 * 8 * MAXI * 4);
  unsigned short* e0t = (unsigned short*)qh;    // 16 MB (qh+ql)
  unsigned short* e1a = (unsigned short*)kh;    // 16 MB (kh+kl)
  unsigned short* e2a = (unsigned short*)vth;   // 16 MB (vth+vtl), reused as e2c
  unsigned short* e1b = (unsigned short*)alloc((size_t)NTOK * 2048 * 2);
  unsigned short* e2b = (unsigned short*)alloc((size_t)NTOK * 2048 * 2);
  unsigned short* e3a = (unsigned short*)alloc((size_t)NTOK * 1024 * 2);
  unsigned short* e3b = (unsigned short*)alloc((size_t)NTOK * 2048 * 2);
  unsigned short* e2c = e2a;

  const size_t moff[12] = {0, 2097152, 4194304, 6291456, 8388608, 10485760,
                           12582912, 16777216, 20971520, 23068672, 24117248, 26214400};
  auto mw = [&](int i) -> const unsigned short* { return moeW + moff[i]; };

  // ---- weight conversions ----
  cvt_attn4_k<<<dim3(1024, 4), dim3(256), 0, stream>>>(wq, wk, wv, wo, awh, awl);
  cvt_moe_all_k<<<dim3(4096, 12), dim3(256), 0, stream>>>(
      moesrc[0], moesrc[1], moesrc[2], moesrc[3], moesrc[4], moesrc[5],
      moesrc[6], moesrc[7], moesrc[8], moesrc[9], moesrc[10], moesrc[11], moeW);
  const _Float16* woh = awh + (3 << 20); const _Float16* wol = awl + (3 << 20);

  // ---- attention path (fp16x2) ----
  rms_split_k<<<dim3(NTOK), dim3(256), 0, stream>>>(x, n1w, hh, hl);
  gemm_split_k<3><<<dim3(24, 32), dim3(256), 0, stream>>>(
      hh, hl, awh, awl, 1024, 3072, qh, ql, 1.0f / SW, nullptr, nullptr,
      kh, kl, vth, vtl, qnw, knw);
  attn_k<<<dim3(512), dim3(256), 0, stream>>>(qh, ql, kh, kl, vth, vtl, hh, hl);
  gemm_split_k<1><<<dim3(8, 32), dim3(256), 0, stream>>>(
      hh, hl, woh, wol, 1024, 1024, nullptr, nullptr, 1.0f / (SA * SW), x, outp,
      nullptr, nullptr, nullptr, nullptr, nullptr, nullptr);

  // ---- MoE (sparse top-2, dense work-list phases, scatter into outp) ----
  rmsgate_k<<<dim3(NTOK), dim3(256), 0, stream>>>(outp, n2w, gw, xfb, wts);

  MoeCfg cfg;
  const int nbn_tab[4][4] = {{32, 32, 32, 16},
                             {16, 32, 32, 32},
                             {0, 16, 32, 0},
                             {0, 0, 16, 16}};
  const int ks_tab[4][4]  = {{1, 1, 1, 1},
                             {2, 1, 1, 1},
                             {1, 2, 1, 1},
                             {1, 1, 2, 2}};
  for (int pp = 0; pp < 4; ++pp)
    for (int ee = 0; ee < 4; ++ee) { cfg.nbn[pp][ee] = nbn_tab[pp][ee]; cfg.ks[pp][ee] = ks_tab[pp][ee]; }

  route2_k<<<dim3(1), dim3(256), 0, stream>>>(wts, idxP, meta, work, cfg);

  auto mk = [&](const unsigned short* A, const unsigned short* B, unsigned short* outb,
                const unsigned short* other, int K, int nbn, int act, int ep, int gath, int ks) {
    SubOpP s; s.A = A; s.Bw = B; s.outb = outb; s.other = other;
    s.K = K; s.nbn = nbn; s.act = act; s.ep = ep; s.gath = gath; s.ks = ks;
    return s;
  };
  const SubOpP none = mk(nullptr, nullptr, nullptr, nullptr, 1024, 0, 0, 0, 0, 1);

  PhaseP p1;
  p1.op[0] = mk(xfb, mw(0), e0t, nullptr, 1024, 32, 1, 0, 1, 1);  // e0: gelu(x@up)
  p1.op[1] = mk(xfb, mw(3), e1a, nullptr, 1024, 32, 0, 0, 1, 1);  // e1: x@w2 raw
  p1.op[2] = mk(xfb, mw(5), e2a, nullptr, 1024, 32, 1, 0, 1, 1);  // e2: gelu(x@l1)
  p1.op[3] = mk(xfb, mw(9), e3a, nullptr, 1024, 16, 1, 0, 1, 1);  // e3: gelu(x@dn)
  gemm_moe_k<<<dim3(8, MAXI), dim3(256), 0, stream>>>(p1, meta, idxP, wts, outp, work);

  PhaseP p2;
  p2.op[0] = mk(e0t, mw(1), nullptr, nullptr, 2048, 16, 0, 2, 0, 2);  // e0 down -> outp
  p2.op[1] = mk(xfb, mw(2), e1b, e1a, 1024, 32, 0, 1, 1, 1);          // e1: silu(x@w1)*e1a
  p2.op[2] = mk(e2a, mw(6), e2b, nullptr, 2048, 32, 1, 0, 0, 1);      // e2: gelu(@l2)
  p2.op[3] = mk(e3a, mw(10), e3b, nullptr, 1024, 32, 1, 0, 0, 1);     // e3: gelu(@up)
  gemm_moe_k<<<dim3(8, MAXI), dim3(256), 0, stream>>>(p2, meta, idxP, wts, outp, work + 8 * MAXI);

  PhaseP p3;
  p3.op[0] = none;
  p3.op[1] = mk(e1b, mw(4), nullptr, nullptr, 2048, 16, 0, 2, 0, 2);  // e1 down -> outp
  p3.op[2] = mk(e2b, mw(7), e2c, nullptr, 2048, 32, 1, 0, 0, 1);      // e2: gelu(@l3)
  p3.op[3] = none;
  gemm_moe_k<<<dim3(8, MAXI), dim3(256), 0, stream>>>(p3, meta, idxP, wts, outp, work + 16 * MAXI);

  PhaseP p4;
  p4.op[0] = none;
  p4.op[1] = none;
  p4.op[2] = mk(e2c, mw(8), nullptr, nullptr, 2048, 16, 0, 2, 0, 2);  // e2 l4 -> outp
  p4.op[3] = mk(e3b, mw(11), nullptr, nullptr, 2048, 16, 0, 2, 0, 2); // e3 out -> outp
  gemm_moe_k<<<dim3(8, MAXI), dim3(256), 0, stream>>>(p4, meta, idxP, wts, outp, work + 24 * MAXI);
}